// Round 3
// baseline (532.515 us; speedup 1.0000x reference)
//
#include <hip/hip_runtime.h>
#include <stdint.h>

typedef _Float16 f16x8 __attribute__((ext_vector_type(8)));
typedef _Float16 f16x4 __attribute__((ext_vector_type(4)));
typedef float fx4 __attribute__((ext_vector_type(4)));

static constexpr int S_LEN = 2048;
static constexpr int BATCH = 2;
static constexpr int TOKENS = BATCH * S_LEN;   // 4096
static constexpr int DIM = 2048;
static constexpr int NH = 16;
static constexpr int QR = 1536;
static constexpr int KVR = 512;
static constexpr int DN = 128;
static constexpr int DR = 64;
static constexpr int DV = 128;

// async global->LDS, 16B per lane; LDS dest = wave-uniform base, HW adds lane*16
__device__ __forceinline__ void async16(const _Float16* g, _Float16* lds_base_uniform) {
  __builtin_amdgcn_global_load_lds(
      (const __attribute__((address_space(1))) void*)g,
      (__attribute__((address_space(3))) void*)lds_base_uniform, 16, 0, 0);
}

// raw barrier WITHOUT the implicit vmcnt(0) drain of __syncthreads
__device__ __forceinline__ void bar() {
  asm volatile("" ::: "memory");
  __builtin_amdgcn_s_barrier();
  asm volatile("" ::: "memory");
}
#define VMWAIT(n) asm volatile("s_waitcnt vmcnt(" #n ")" ::: "memory")

// intra-16-lane rotate via DPP (VALU, ~4cyc vs ~35cyc ds_swizzle)
#define ROR16(x, ctrl) \
  __uint_as_float(__builtin_amdgcn_update_dpp(__float_as_uint(x), __float_as_uint(x), \
                                              (ctrl), 0xF, 0xF, false))

// ---------------- fused f32 -> f16 conversion (all tensors, one dispatch) ---
struct CvtSegs {
  const float* src[8];
  _Float16* dst[8];
  int n4[8];
  int cum[9];
};
__global__ __launch_bounds__(256) void cvt_all(CvtSegs s) {
  const int b = blockIdx.x;
  int seg = 0;
#pragma unroll
  for (int k = 0; k < 7; ++k) seg += (b >= s.cum[seg + 1]) ? 1 : 0;
  const int i = (b - s.cum[seg]) * 256 + threadIdx.x;
  if (i >= s.n4[seg]) return;
  fx4 v = *(const fx4*)(s.src[seg] + (size_t)i * 4);
  f16x4 o;
  o[0] = (_Float16)v[0]; o[1] = (_Float16)v[1];
  o[2] = (_Float16)v[2]; o[3] = (_Float16)v[3];
  *(f16x4*)(s.dst[seg] + (size_t)i * 4) = o;
}

// ---------------- NT GEMM, 3-buffer LDS, counted vmcnt (no drain) ----------
// C[M,N] = A[M,K] * W[N,K]^T.  128x128 tile, BK=32.
// Loop: vmcnt(4) [tile kt landed] -> s_barrier -> stage kt+2 -> compute kt.
// Stage targets the buffer last read one iteration before the barrier: safe.
// MODE 0: f16 C0.  MODE 1: f32 C0.  MODE 2: split knope[T,2048] + vT[2048,T].
// MODE 3: split qnope[.,2048] + qpe[.,1024].  MODE 4: split kvc[.,512] + krope[.,64].
template <int MODE>
__global__ __launch_bounds__(256) void gemm_nt(const _Float16* __restrict__ A,
                                               const _Float16* __restrict__ W,
                                               void* __restrict__ C0v,
                                               void* __restrict__ C1v,
                                               int M, int N, int K) {
  __shared__ __attribute__((aligned(16))) _Float16 As[3][128 * 32];
  __shared__ __attribute__((aligned(16))) _Float16 Ws[3][128 * 32];
  const int tid = threadIdx.x;
  const int lane = tid & 63;
  const int wave = tid >> 6;
  const int wr = (wave >> 1) * 64;
  const int wc = (wave & 1) * 64;
  const int m16 = lane & 15;
  const int quad = lane >> 4;
  const int m0 = blockIdx.y * 128;
  const int n0 = blockIdx.x * 128;

  auto stage = [&](int buf, int k0) {
#pragma unroll
    for (int p = 0; p < 2; ++p) {
      const int cb = p * 256 + wave * 64;   // wave-uniform chunk base
      const int ch = cb + lane;
      const int r = ch >> 2;
      const int c8 = (ch & 3) * 8;
      // W rows n0+r may exceed N (N=576 gemm); reads stay inside workspace.
      async16(A + (size_t)(m0 + r) * K + k0 + c8, &As[buf][cb * 8]);
      async16(W + (size_t)(n0 + r) * K + k0 + c8, &Ws[buf][cb * 8]);
    }
  };

  const fx4 fz = {0.f, 0.f, 0.f, 0.f};
  fx4 acc[4][4];
#pragma unroll
  for (int i = 0; i < 4; ++i)
#pragma unroll
    for (int j = 0; j < 4; ++j) acc[i][j] = fz;

  const int nkt = K >> 5;                  // >= 16 for all our shapes
  stage(0, 0);
  stage(1, 32);
  int cur = 0;
  for (int kt = 0; kt < nkt; ++kt) {
    if (kt + 1 < nkt) { VMWAIT(4); } else { VMWAIT(0); }   // tile kt landed (4 loads/wave/stage)
    bar();
    if (kt + 2 < nkt) {
      int b2 = cur + 2; if (b2 >= 3) b2 -= 3;
      stage(b2, (kt + 2) * 32);            // buffer last read 1 iter before barrier: safe
    }
    const _Float16* as = As[cur];
    const _Float16* ws = Ws[cur];
    f16x8 af[4], wf[4];
#pragma unroll
    for (int i = 0; i < 4; ++i)
      af[i] = *(const f16x8*)(&as[(wr + i * 16 + m16) * 32 + quad * 8]);
#pragma unroll
    for (int j = 0; j < 4; ++j)
      wf[j] = *(const f16x8*)(&ws[(wc + j * 16 + m16) * 32 + quad * 8]);
#pragma unroll
    for (int i = 0; i < 4; ++i)
#pragma unroll
      for (int j = 0; j < 4; ++j)
        acc[i][j] = __builtin_amdgcn_mfma_f32_16x16x32_f16(af[i], wf[j], acc[i][j], 0, 0, 0);
    if (++cur == 3) cur = 0;
  }

#pragma unroll
  for (int j = 0; j < 4; ++j) {
    const int col = n0 + wc + j * 16 + m16;
    if (MODE == 2) {
      _Float16* KN = (_Float16*)C0v;
      _Float16* VT = (_Float16*)C1v;
      const int head = col >> 8;
      const int sub = col & 255;
      if (sub < 128) {
#pragma unroll
        for (int i = 0; i < 4; ++i)
#pragma unroll
          for (int r = 0; r < 4; ++r)
            KN[(size_t)(m0 + wr + i * 16 + quad * 4 + r) * 2048 + head * 128 + sub] =
                (_Float16)acc[i][j][r];
      } else {
        const int dv = sub - 128;
#pragma unroll
        for (int i = 0; i < 4; ++i) {
          f16x4 v;
#pragma unroll
          for (int r = 0; r < 4; ++r) v[r] = (_Float16)acc[i][j][r];
          *(f16x4*)(&VT[(size_t)(head * 128 + dv) * TOKENS + m0 + wr + i * 16 + quad * 4]) = v;
        }
      }
    } else if (MODE == 3) {
#pragma unroll
      for (int i = 0; i < 4; ++i)
#pragma unroll
        for (int r = 0; r < 4; ++r) {
          const size_t row = (size_t)(m0 + wr + i * 16 + quad * 4 + r);
          if (col < 2048) ((_Float16*)C0v)[row * 2048 + col] = (_Float16)acc[i][j][r];
          else ((_Float16*)C1v)[row * 1024 + col - 2048] = (_Float16)acc[i][j][r];
        }
    } else if (MODE == 4) {
      if (col < 576) {
#pragma unroll
        for (int i = 0; i < 4; ++i)
#pragma unroll
          for (int r = 0; r < 4; ++r) {
            const size_t row = (size_t)(m0 + wr + i * 16 + quad * 4 + r);
            if (col < 512) ((_Float16*)C0v)[row * 512 + col] = (_Float16)acc[i][j][r];
            else ((_Float16*)C1v)[row * 64 + col - 512] = (_Float16)acc[i][j][r];
          }
      }
    } else {
      if (col < N) {
#pragma unroll
        for (int i = 0; i < 4; ++i)
#pragma unroll
          for (int r = 0; r < 4; ++r) {
            const size_t row = (size_t)(m0 + wr + i * 16 + quad * 4 + r);
            if (MODE == 0) ((_Float16*)C0v)[row * N + col] = (_Float16)acc[i][j][r];
            else ((float*)C0v)[row * N + col] = acc[i][j][r];
          }
      }
    }
  }
}

// ---------------- in-place RMSNorm over f16 rows (fp32 math) ---------------
template <int NC>
__global__ __launch_bounds__(256) void rmsnorm_ip(_Float16* __restrict__ xx,
                                                  const float* __restrict__ w) {
  const int row = blockIdx.x;
  _Float16* p = xx + (size_t)row * NC;
  float ss = 0.f;
  for (int c = threadIdx.x; c < NC; c += 256) {
    const float v = (float)p[c];
    ss += v * v;
  }
#pragma unroll
  for (int d = 1; d < 64; d <<= 1) ss += __shfl_xor(ss, d);
  __shared__ float red[4];
  if ((threadIdx.x & 63) == 0) red[threadIdx.x >> 6] = ss;
  __syncthreads();
  const float rs = rsqrtf((red[0] + red[1] + red[2] + red[3]) * (1.0f / NC) + 1e-6f);
  for (int c = threadIdx.x; c < NC; c += 256)
    p[c] = (_Float16)((float)p[c] * rs * w[c]);
}

// ---------------- in-place RoPE (LLaMA interleaved pairs, d=64) ------------
__global__ void rope_q(_Float16* __restrict__ qpe) {  // [T, NH*64]
  const int idx = blockIdx.x * 256 + threadIdx.x;     // T*NH*32 threads
  const int t = idx >> 9;
  const int rem = idx & 511;
  const int hh = rem >> 5;
  const int i = rem & 31;
  const int s = t & (S_LEN - 1);
  const float fr = exp2f(-(float)i * 0.4152410118609203f);  // log2(1e4)/32
  const float ang = (float)s * fr;
  const float sn = sinf(ang), cs = cosf(ang);
  const size_t base = (size_t)t * (NH * DR) + hh * DR + 2 * i;
  const float x1 = (float)qpe[base];
  const float x2 = (float)qpe[base + 1];
  qpe[base] = (_Float16)(x1 * cs - x2 * sn);
  qpe[base + 1] = (_Float16)(x1 * sn + x2 * cs);
}

__global__ void rope_k(_Float16* __restrict__ kr) {  // [T, 64]
  const int idx = blockIdx.x * 256 + threadIdx.x;    // T*32 threads
  const int t = idx >> 5;
  const int i = idx & 31;
  const int s = t & (S_LEN - 1);
  const float fr = exp2f(-(float)i * 0.4152410118609203f);
  const float ang = (float)s * fr;
  const float sn = sinf(ang), cs = cosf(ang);
  const size_t base = (size_t)t * DR + 2 * i;
  const float x1 = (float)kr[base];
  const float x2 = (float)kr[base + 1];
  kr[base] = (_Float16)(x1 * cs - x2 * sn);
  kr[base + 1] = (_Float16)(x1 * sn + x2 * cs);
}

// ---------------- causal flash attention v6 --------------------------------
// Block = 4 waves x 16 q-rows; TWO complementary q-tiles (j,31-j) -> uniform
// 66 K-tiles/block. K-tile (32x192) + V-tile (32x128) staged via
// global_load_lds into a 3-buffer rotation with counted vmcnt:
//   vmcnt(5) [tile kt landed] -> s_barrier -> stage kt+2 -> compute kt.
// No vmcnt(0) drain in steady state; loads span a full tile of compute.
// Vs is XOR-swizzled (chunk ^= (chunk>>3)&3, involution) so the B-fragment
// ds_read_b128 spreads 16 consecutive lanes over 8 bank-slots (2-way = free).
// DPP softmax reductions, log2 domain, defer-max.
__global__ __launch_bounds__(256, 2) void mla_attn(
    const _Float16* __restrict__ qn,   // [T, NH*128]
    const _Float16* __restrict__ qp,   // [T, NH*64]  roped
    const _Float16* __restrict__ kn,   // [T, NH*128]
    const _Float16* __restrict__ kr,   // [T, 64]     roped
    const _Float16* __restrict__ vT,   // [NH*128, T]
    _Float16* __restrict__ out)        // [T, NH*128]
{
  // chunk-major K: chunk c = ch*32+key (ch 0..23 = 16B chunk of 192-dim, key 0..31)
  __shared__ __attribute__((aligned(16))) _Float16 Ks[3][768 * 8];  // 36 KB
  __shared__ __attribute__((aligned(16))) _Float16 Vs[3][512 * 8];  // 24 KB
  __shared__ __attribute__((aligned(16))) _Float16 Ps[4][16][40];   // 5 KB

  const int bid = blockIdx.x;          // 512 = B * NH * 16 pairs
  const int b = bid >> 8;
  const int u = bid & 255;
  const int h = u >> 4;
  const int jp = u & 15;               // pair index
  const int tok0 = b * S_LEN;

  const int tid = threadIdx.x;
  const int lane = tid & 63;
  const int wave = tid >> 6;
  const int m16 = lane & 15;
  const int quad = lane >> 4;

  auto stageKV = [&](int buf, int kbase) {
#pragma unroll
    for (int j = 0; j < 3; ++j) {
      const int i = wave * 3 + j;             // instr 0..11
      const int ch = i * 2 + (lane >> 5);     // wave-uniform side of 16
      const int key = lane & 31;
      const _Float16* g = (ch < 16)
          ? kn + (size_t)(tok0 + kbase + key) * 2048 + h * 128 + ch * 8
          : kr + (size_t)(tok0 + kbase + key) * 64 + (ch - 16) * 8;
      async16(g, &Ks[buf][i * 512]);
    }
#pragma unroll
    for (int j = 0; j < 2; ++j) {
      const int i = wave * 2 + j;             // instr 0..7
      const int p = i * 64 + lane;            // LDS chunk position 0..511
      const int L = p ^ ((p >> 3) & 3);       // involutive source pre-swizzle
      const int dv = L >> 2;
      const int qc = L & 3;
      async16(vT + (size_t)(h * 128 + dv) * TOKENS + tok0 + kbase + qc * 8,
              &Vs[buf][i * 512]);
    }
  };

  const float scale2 = 0.07216878364870323f * 1.4426950408889634f;  // /sqrt(192), log2 dom
  const fx4 fz = {0.f, 0.f, 0.f, 0.f};

  for (int half = 0; half < 2; ++half) {
    const int q32 = half ? (31 - jp) : jp;    // 64-row q-tile index
    const int qb = q32 * 64;
    const int R0 = qb + wave * 16;            // this wave's first q-row

    // ---- Q fragments (A-layout), loaded once per half ----
    f16x8 qf[6];
    {
      const size_t t = (size_t)(tok0 + qb + wave * 16 + m16);
#pragma unroll
      for (int kk = 0; kk < 4; ++kk)
        qf[kk] = *(const f16x8*)(qn + t * 2048 + h * 128 + kk * 32 + quad * 8);
#pragma unroll
      for (int kk = 0; kk < 2; ++kk)
        qf[4 + kk] = *(const f16x8*)(qp + t * 1024 + h * 64 + kk * 32 + quad * 8);
    }

    fx4 oacc[8];
#pragma unroll
    for (int n = 0; n < 8; ++n) oacc[n] = fz;
    float mst[4], lst[4];
#pragma unroll
    for (int r = 0; r < 4; ++r) { mst[r] = -3.0e38f; lst[r] = 0.f; }

    const int nkt = (qb >> 5) + 2;            // key tiles: 0 .. qb+63 (>= 2)

    bar();                                    // prev-half readers done before restage
    stageKV(0, 0);
    stageKV(1, 32);
    int cur = 0;
    for (int kt = 0; kt < nkt; ++kt) {
      const int kbase = kt * 32;
      if (kt + 1 < nkt) { VMWAIT(5); } else { VMWAIT(0); }  // tile kt landed (5 loads/wave)
      bar();
      if (kt + 2 < nkt) {
        int b2 = cur + 2; if (b2 >= 3) b2 -= 3;
        stageKV(b2, kbase + 64);              // buffer last read 1 iter before barrier
      }
      const bool live = (kbase <= R0 + 15);
      if (!live) { if (++cur == 3) cur = 0; continue; }
      const _Float16* ks = Ks[cur];
      const _Float16* vs = Vs[cur];

      // ---- S = Q K^T : 2 key-groups x 6 kk ----
      fx4 sc[2];
      sc[0] = fz; sc[1] = fz;
      __builtin_amdgcn_s_setprio(1);
#pragma unroll
      for (int kk = 0; kk < 6; ++kk) {
#pragma unroll
        for (int n = 0; n < 2; ++n) {
          f16x8 kf = *(const f16x8*)(&ks[(kk * 128 + quad * 32 + n * 16 + m16) * 8]);
          sc[n] = __builtin_amdgcn_mfma_f32_16x16x32_f16(qf[kk], kf, sc[n], 0, 0, 0);
        }
      }
      __builtin_amdgcn_s_setprio(0);

      // V fragments from LDS (B-layout), swizzled read: issued now, used at PV
      f16x8 vf[8];
#pragma unroll
      for (int n8 = 0; n8 < 8; ++n8) {
        const int c0 = (n8 * 16 + m16) * 4 + quad;
        vf[n8] = *(const f16x8*)(&vs[(c0 ^ ((c0 >> 3) & 3)) * 8]);
      }

      // ---- online softmax, log2 dom, DPP reduce (row=quad*4+r, col=n*16+m16) ----
      const bool needmask = (kbase + 31 > R0);
      float alpha[4];
      bool any_upd = false;
#pragma unroll
      for (int r = 0; r < 4; ++r) {
        float v0 = sc[0][r] * scale2;
        float v1 = sc[1][r] * scale2;
        if (needmask) {
          const int qrow = R0 + quad * 4 + r;
          if (kbase + m16 > qrow)      v0 = -3.0e38f;
          if (kbase + 16 + m16 > qrow) v1 = -3.0e38f;
        }
        float mx = fmaxf(v0, v1);
        mx = fmaxf(mx, ROR16(mx, 0x128));
        mx = fmaxf(mx, ROR16(mx, 0x124));
        mx = fmaxf(mx, ROR16(mx, 0x122));
        mx = fmaxf(mx, ROR16(mx, 0x121));
        float al = 1.0f;
        if (__any(mx > mst[r] + 10.0f)) {     // defer-max: only rescale on real growth
          const float mn = fmaxf(mst[r], mx);
          al = exp2f(mst[r] - mn);
          mst[r] = mn;
          any_upd = true;
        }
        alpha[r] = al;
        const float p0 = exp2f(v0 - mst[r]);
        const float p1 = exp2f(v1 - mst[r]);
        float ls = p0 + p1;
        ls += ROR16(ls, 0x128);
        ls += ROR16(ls, 0x124);
        ls += ROR16(ls, 0x122);
        ls += ROR16(ls, 0x121);
        lst[r] = lst[r] * al + ls;
        _Float16* pr = &Ps[wave][quad * 4 + r][0];
        pr[m16] = (_Float16)p0;
        pr[16 + m16] = (_Float16)p1;
      }
      if (any_upd) {
#pragma unroll
        for (int n8 = 0; n8 < 8; ++n8)
#pragma unroll
          for (int r = 0; r < 4; ++r) oacc[n8][r] *= alpha[r];
      }

      // ---- O += P V  (P via wave-private LDS -> A-layout; V from regs) ----
      f16x8 pf = *(const f16x8*)(&Ps[wave][m16][quad * 8]);
      __builtin_amdgcn_s_setprio(1);
#pragma unroll
      for (int n8 = 0; n8 < 8; ++n8)
        oacc[n8] = __builtin_amdgcn_mfma_f32_16x16x32_f16(pf, vf[n8], oacc[n8], 0, 0, 0);
      __builtin_amdgcn_s_setprio(0);
      if (++cur == 3) cur = 0;
    }

    // ---- epilogue for this half ----
    float inv[4];
#pragma unroll
    for (int r = 0; r < 4; ++r) inv[r] = 1.0f / lst[r];
#pragma unroll
    for (int n8 = 0; n8 < 8; ++n8) {
#pragma unroll
      for (int r = 0; r < 4; ++r) {
        const size_t t = (size_t)(tok0 + qb + wave * 16 + quad * 4 + r);
        out[t * 2048 + h * 128 + n8 * 16 + m16] = (_Float16)(oacc[n8][r] * inv[r]);
      }
    }
  }
}

// ---------------- launch ----------------------------------------------------
extern "C" void kernel_launch(void* const* d_in, const int* in_sizes, int n_in,
                              void* d_out, int out_size, void* d_ws, size_t ws_size,
                              hipStream_t stream) {
  const float* x         = (const float*)d_in[0];
  const float* wq_down   = (const float*)d_in[1];
  const float* q_norm_w  = (const float*)d_in[2];
  const float* wq_up     = (const float*)d_in[3];
  const float* wq_rope   = (const float*)d_in[4];
  const float* wkv_down  = (const float*)d_in[5];
  const float* kv_norm_w = (const float*)d_in[6];
  const float* wkv_up    = (const float*)d_in[7];
  const float* wk_rope   = (const float*)d_in[8];
  const float* wo        = (const float*)d_in[9];
  float* out = (float*)d_out;

  char* ws = (char*)d_ws;
  size_t off = 0;
  auto alloc = [&](size_t bytes) {
    char* p = ws + off;
    off += (bytes + 255) & ~(size_t)255;
    return p;
  };
  _Float16* x_h     = (_Float16*)alloc((size_t)TOKENS * DIM * 2);
  _Float16* wqd_h   = (_Float16*)alloc((size_t)QR * DIM * 2);
  _Float16* wquqr_h = (_Float16*)alloc((size_t)3072 * QR * 2);       // wq_up | wq_rope
  _Float16* wkvdr_h = (_Float16*)alloc((size_t)576 * DIM * 2);       // wkv_down | wk_rope
  _Float16* wkvu_h  = (_Float16*)alloc((size_t)NH * 256 * KVR * 2);
  _Float16* wo_h    = (_Float16*)alloc((size_t)DIM * NH * DV * 2);
  _Float16* qc_h    = (_Float16*)alloc((size_t)TOKENS * QR * 2);
  _Float16* kvc_h   = (_Float16*)alloc((size_t)TOKENS * KVR * 2);
  _Float16* qnope_h = (_Float16*)alloc((size_t)TOKENS * 2048 * 2);
  _Float16* qpe_h   = (_Float16*)alloc((size_t)TOKENS * 1024 * 2);
  _Float16* knope_h = (_Float16*)alloc((size_t)TOKENS * 2048 * 2);
  _Float16* vT_h    = (_Float16*)alloc((size_t)2048 * TOKENS * 2);
  _Float16* krope_h = (_Float16*)alloc((size_t)TOKENS * DR * 2);
  _Float16* attn_h  = (_Float16*)alloc((size_t)TOKENS * 2048 * 2);

  // ---- one fused conversion dispatch ----
  CvtSegs cs;
  const float* srcs[8] = {x, wq_down, wq_up, wq_rope, wkv_down, wk_rope, wkv_up, wo};
  _Float16* dsts[8] = {x_h, wqd_h, wquqr_h, wquqr_h + (size_t)2048 * QR,
                       wkvdr_h, wkvdr_h + (size_t)512 * DIM, wkvu_h, wo_h};
  const size_t ns[8] = {(size_t)TOKENS * DIM, (size_t)QR * DIM, (size_t)2048 * QR,
                        (size_t)1024 * QR, (size_t)KVR * DIM, (size_t)DR * DIM,
                        (size_t)NH * 256 * KVR, (size_t)DIM * NH * DV};
  int cum = 0;
  for (int i = 0; i < 8; ++i) {
    cs.src[i] = srcs[i];
    cs.dst[i] = dsts[i];
    cs.n4[i] = (int)(ns[i] / 4);
    cs.cum[i] = cum;
    cum += (cs.n4[i] + 255) / 256;
  }
  cs.cum[8] = cum;
  cvt_all<<<dim3(cum), 256, 0, stream>>>(cs);

  auto gx = [](int n) { return (unsigned)((n + 127) / 128); };
  const unsigned gm = TOKENS / 128;

  // q path: x -> qc (N=1536)
  gemm_nt<0><<<dim3(gx(QR), gm), 256, 0, stream>>>(x_h, wqd_h, qc_h, nullptr, TOKENS, QR, DIM);
  rmsnorm_ip<QR><<<dim3(TOKENS), 256, 0, stream>>>(qc_h, q_norm_w);
  // kv path fused with rope-key: x -> kvc | krope (N=576)
  gemm_nt<4><<<dim3(gx(576), gm), 256, 0, stream>>>(x_h, wkvdr_h, kvc_h, krope_h, TOKENS, 576, DIM);
  rmsnorm_ip<KVR><<<dim3(TOKENS), 256, 0, stream>>>(kvc_h, kv_norm_w);
  rope_k<<<dim3(TOKENS * 32 / 256), 256, 0, stream>>>(krope_h);
  // q up fused: qc -> qnope | qpe (N=3072)
  gemm_nt<3><<<dim3(gx(3072), gm), 256, 0, stream>>>(qc_h, wquqr_h, qnope_h, qpe_h, TOKENS, 3072, QR);
  rope_q<<<dim3(TOKENS * NH * 32 / 256), 256, 0, stream>>>(qpe_h);
  // kv up-projection, split epilogue: k_nope natural + V transposed
  gemm_nt<2><<<dim3(gx(4096), gm), 256, 0, stream>>>(kvc_h, wkvu_h, knope_h, vT_h, TOKENS, 4096, KVR);
  // attention: 512 blocks, each = one (b,h, complementary q-tile pair), uniform work
  mla_attn<<<dim3(512), 256, 0, stream>>>(qnope_h, qpe_h, knope_h, krope_h, vT_h, attn_h);
  // output projection (fp32 out)
  gemm_nt<1><<<dim3(gx(DIM), gm), 256, 0, stream>>>(attn_h, wo_h, out, nullptr, TOKENS, DIM, NH * DV);
}

// Round 5
// 512.352 us; speedup vs baseline: 1.0394x; 1.0394x over previous
//
#include <hip/hip_runtime.h>
#include <stdint.h>

typedef _Float16 f16x8 __attribute__((ext_vector_type(8)));
typedef _Float16 f16x4 __attribute__((ext_vector_type(4)));
typedef float fx4 __attribute__((ext_vector_type(4)));

static constexpr int S_LEN = 2048;
static constexpr int BATCH = 2;
static constexpr int TOKENS = BATCH * S_LEN;   // 4096
static constexpr int DIM = 2048;
static constexpr int NH = 16;
static constexpr int QR = 1536;
static constexpr int KVR = 512;
static constexpr int DN = 128;
static constexpr int DR = 64;
static constexpr int DV = 128;

// async global->LDS, 16B per lane; LDS dest = wave-uniform base, HW adds lane*16
__device__ __forceinline__ void async16(const _Float16* g, _Float16* lds_base_uniform) {
  __builtin_amdgcn_global_load_lds(
      (const __attribute__((address_space(1))) void*)g,
      (__attribute__((address_space(3))) void*)lds_base_uniform, 16, 0, 0);
}

// raw barrier WITHOUT the implicit vmcnt(0) drain of __syncthreads
__device__ __forceinline__ void bar() {
  asm volatile("" ::: "memory");
  __builtin_amdgcn_s_barrier();
  asm volatile("" ::: "memory");
}
#define VMWAIT(n) asm volatile("s_waitcnt vmcnt(" #n ")" ::: "memory")

// intra-16-lane rotate via DPP (VALU, ~4cyc vs ~35cyc ds_swizzle)
#define ROR16(x, ctrl) \
  __uint_as_float(__builtin_amdgcn_update_dpp(__float_as_uint(x), __float_as_uint(x), \
                                              (ctrl), 0xF, 0xF, false))

// ---------------- fused f32 -> f16 conversion (all tensors, one dispatch) ---
struct CvtSegs {
  const float* src[8];
  _Float16* dst[8];
  int n4[8];
  int cum[9];
};
__global__ __launch_bounds__(256) void cvt_all(CvtSegs s) {
  const int b = blockIdx.x;
  int seg = 0;
#pragma unroll
  for (int k = 0; k < 7; ++k) seg += (b >= s.cum[seg + 1]) ? 1 : 0;
  const int i = (b - s.cum[seg]) * 256 + threadIdx.x;
  if (i >= s.n4[seg]) return;
  fx4 v = *(const fx4*)(s.src[seg] + (size_t)i * 4);
  f16x4 o;
  o[0] = (_Float16)v[0]; o[1] = (_Float16)v[1];
  o[2] = (_Float16)v[2]; o[3] = (_Float16)v[3];
  *(f16x4*)(s.dst[seg] + (size_t)i * 4) = o;
}

// ---------------- NT GEMM, 3-buffer LDS, counted vmcnt (no drain) ----------
// C[M,N] = A[M,K] * W[N,K]^T.  128x128 tile, BK=32.
// Loop: vmcnt(4) [tile kt landed] -> s_barrier -> stage kt+2 -> compute kt.
// Stage targets the buffer last read one iteration before the barrier: safe.
// MODE 0: f16 C0.  MODE 1: f32 C0.  MODE 2: split knope[T,2048] + vT[2048,T].
// MODE 3: split qnope[.,2048] + qpe[.,1024].  MODE 4: split kvc[.,512] + krope[.,64].
template <int MODE>
__global__ __launch_bounds__(256) void gemm_nt(const _Float16* __restrict__ A,
                                               const _Float16* __restrict__ W,
                                               void* __restrict__ C0v,
                                               void* __restrict__ C1v,
                                               int M, int N, int K) {
  __shared__ __attribute__((aligned(16))) _Float16 As[3][128 * 32];
  __shared__ __attribute__((aligned(16))) _Float16 Ws[3][128 * 32];
  const int tid = threadIdx.x;
  const int lane = tid & 63;
  const int wave = tid >> 6;
  const int wr = (wave >> 1) * 64;
  const int wc = (wave & 1) * 64;
  const int m16 = lane & 15;
  const int quad = lane >> 4;
  const int m0 = blockIdx.y * 128;
  const int n0 = blockIdx.x * 128;

  auto stage = [&](int buf, int k0) {
#pragma unroll
    for (int p = 0; p < 2; ++p) {
      const int cb = p * 256 + wave * 64;   // wave-uniform chunk base
      const int ch = cb + lane;
      const int r = ch >> 2;
      const int c8 = (ch & 3) * 8;
      // W rows n0+r may exceed N (N=576 gemm); reads stay inside workspace.
      async16(A + (size_t)(m0 + r) * K + k0 + c8, &As[buf][cb * 8]);
      async16(W + (size_t)(n0 + r) * K + k0 + c8, &Ws[buf][cb * 8]);
    }
  };

  const fx4 fz = {0.f, 0.f, 0.f, 0.f};
  fx4 acc[4][4];
#pragma unroll
  for (int i = 0; i < 4; ++i)
#pragma unroll
    for (int j = 0; j < 4; ++j) acc[i][j] = fz;

  const int nkt = K >> 5;                  // >= 16 for all our shapes
  stage(0, 0);
  stage(1, 32);
  int cur = 0;
  for (int kt = 0; kt < nkt; ++kt) {
    if (kt + 1 < nkt) { VMWAIT(4); } else { VMWAIT(0); }   // tile kt landed (4 loads/wave/stage)
    bar();
    if (kt + 2 < nkt) {
      int b2 = cur + 2; if (b2 >= 3) b2 -= 3;
      stage(b2, (kt + 2) * 32);            // buffer last read 1 iter before barrier: safe
    }
    const _Float16* as = As[cur];
    const _Float16* ws = Ws[cur];
    f16x8 af[4], wf[4];
#pragma unroll
    for (int i = 0; i < 4; ++i)
      af[i] = *(const f16x8*)(&as[(wr + i * 16 + m16) * 32 + quad * 8]);
#pragma unroll
    for (int j = 0; j < 4; ++j)
      wf[j] = *(const f16x8*)(&ws[(wc + j * 16 + m16) * 32 + quad * 8]);
#pragma unroll
    for (int i = 0; i < 4; ++i)
#pragma unroll
      for (int j = 0; j < 4; ++j)
        acc[i][j] = __builtin_amdgcn_mfma_f32_16x16x32_f16(af[i], wf[j], acc[i][j], 0, 0, 0);
    if (++cur == 3) cur = 0;
  }

#pragma unroll
  for (int j = 0; j < 4; ++j) {
    const int col = n0 + wc + j * 16 + m16;
    if (MODE == 2) {
      _Float16* KN = (_Float16*)C0v;
      _Float16* VT = (_Float16*)C1v;
      const int head = col >> 8;
      const int sub = col & 255;
      if (sub < 128) {
#pragma unroll
        for (int i = 0; i < 4; ++i)
#pragma unroll
          for (int r = 0; r < 4; ++r)
            KN[(size_t)(m0 + wr + i * 16 + quad * 4 + r) * 2048 + head * 128 + sub] =
                (_Float16)acc[i][j][r];
      } else {
        const int dv = sub - 128;
#pragma unroll
        for (int i = 0; i < 4; ++i) {
          f16x4 v;
#pragma unroll
          for (int r = 0; r < 4; ++r) v[r] = (_Float16)acc[i][j][r];
          *(f16x4*)(&VT[(size_t)(head * 128 + dv) * TOKENS + m0 + wr + i * 16 + quad * 4]) = v;
        }
      }
    } else if (MODE == 3) {
#pragma unroll
      for (int i = 0; i < 4; ++i)
#pragma unroll
        for (int r = 0; r < 4; ++r) {
          const size_t row = (size_t)(m0 + wr + i * 16 + quad * 4 + r);
          if (col < 2048) ((_Float16*)C0v)[row * 2048 + col] = (_Float16)acc[i][j][r];
          else ((_Float16*)C1v)[row * 1024 + col - 2048] = (_Float16)acc[i][j][r];
        }
    } else if (MODE == 4) {
      if (col < 576) {
#pragma unroll
        for (int i = 0; i < 4; ++i)
#pragma unroll
          for (int r = 0; r < 4; ++r) {
            const size_t row = (size_t)(m0 + wr + i * 16 + quad * 4 + r);
            if (col < 512) ((_Float16*)C0v)[row * 512 + col] = (_Float16)acc[i][j][r];
            else ((_Float16*)C1v)[row * 64 + col - 512] = (_Float16)acc[i][j][r];
          }
      }
    } else {
      if (col < N) {
#pragma unroll
        for (int i = 0; i < 4; ++i)
#pragma unroll
          for (int r = 0; r < 4; ++r) {
            const size_t row = (size_t)(m0 + wr + i * 16 + quad * 4 + r);
            if (MODE == 0) ((_Float16*)C0v)[row * N + col] = (_Float16)acc[i][j][r];
            else ((float*)C0v)[row * N + col] = acc[i][j][r];
          }
      }
    }
  }
}

// ---------------- in-place RMSNorm over f16 rows (fp32 math) ---------------
template <int NC>
__global__ __launch_bounds__(256) void rmsnorm_ip(_Float16* __restrict__ xx,
                                                  const float* __restrict__ w) {
  const int row = blockIdx.x;
  _Float16* p = xx + (size_t)row * NC;
  float ss = 0.f;
  for (int c = threadIdx.x; c < NC; c += 256) {
    const float v = (float)p[c];
    ss += v * v;
  }
#pragma unroll
  for (int d = 1; d < 64; d <<= 1) ss += __shfl_xor(ss, d);
  __shared__ float red[4];
  if ((threadIdx.x & 63) == 0) red[threadIdx.x >> 6] = ss;
  __syncthreads();
  const float rs = rsqrtf((red[0] + red[1] + red[2] + red[3]) * (1.0f / NC) + 1e-6f);
  for (int c = threadIdx.x; c < NC; c += 256)
    p[c] = (_Float16)((float)p[c] * rs * w[c]);
}

// ---------------- in-place RoPE (LLaMA interleaved pairs, d=64) ------------
__global__ void rope_q(_Float16* __restrict__ qpe) {  // [T, NH*64]
  const int idx = blockIdx.x * 256 + threadIdx.x;     // T*NH*32 threads
  const int t = idx >> 9;
  const int rem = idx & 511;
  const int hh = rem >> 5;
  const int i = rem & 31;
  const int s = t & (S_LEN - 1);
  const float fr = exp2f(-(float)i * 0.4152410118609203f);  // log2(1e4)/32
  const float ang = (float)s * fr;
  const float sn = sinf(ang), cs = cosf(ang);
  const size_t base = (size_t)t * (NH * DR) + hh * DR + 2 * i;
  const float x1 = (float)qpe[base];
  const float x2 = (float)qpe[base + 1];
  qpe[base] = (_Float16)(x1 * cs - x2 * sn);
  qpe[base + 1] = (_Float16)(x1 * sn + x2 * cs);
}

__global__ void rope_k(_Float16* __restrict__ kr) {  // [T, 64]
  const int idx = blockIdx.x * 256 + threadIdx.x;    // T*32 threads
  const int t = idx >> 5;
  const int i = idx & 31;
  const int s = t & (S_LEN - 1);
  const float fr = exp2f(-(float)i * 0.4152410118609203f);
  const float ang = (float)s * fr;
  const float sn = sinf(ang), cs = cosf(ang);
  const size_t base = (size_t)t * DR + 2 * i;
  const float x1 = (float)kr[base];
  const float x2 = (float)kr[base + 1];
  kr[base] = (_Float16)(x1 * cs - x2 * sn);
  kr[base + 1] = (_Float16)(x1 * sn + x2 * cs);
}

// ---------------- causal flash attention v7 --------------------------------
// ONE 64-row q-tile per block (4 waves x 16 rows), grid = B*NH*32 = 1024
// blocks, dispatched LONGEST-FIRST (q32 = 31 - (bid>>5)) so big blocks start
// first and small ones backfill -> dynamic balance at 3 blocks/CU.
// LDS = 45KB (2-buffer K 24K + V 16K + P 5K) -> 3 blocks/CU resident:
// cross-block TLP hides the per-tile barrier drain and softmax chains.
// K-tile (32x192) + V-tile (32x128) staged via global_load_lds, double-
// buffered, ONE __syncthreads per tile. Vs XOR-swizzled (2-way = free).
// DPP softmax reductions, log2 domain, defer-max.
__global__ __launch_bounds__(256, 2) void mla_attn(
    const _Float16* __restrict__ qn,   // [T, NH*128]
    const _Float16* __restrict__ qp,   // [T, NH*64]  roped
    const _Float16* __restrict__ kn,   // [T, NH*128]
    const _Float16* __restrict__ kr,   // [T, 64]     roped
    const _Float16* __restrict__ vT,   // [NH*128, T]
    _Float16* __restrict__ out)        // [T, NH*128]
{
  // chunk-major K: chunk c = ch*32+key (ch 0..23 = 16B chunk of 192-dim, key 0..31)
  __shared__ __attribute__((aligned(16))) _Float16 Ks[2][768 * 8];  // 24 KB
  __shared__ __attribute__((aligned(16))) _Float16 Vs[2][512 * 8];  // 16 KB
  __shared__ __attribute__((aligned(16))) _Float16 Ps[4][16][40];   // 5 KB

  const int bid = blockIdx.x;          // 1024 = 32 q-tiles (longest first) x 32 (b,h)
  const int j = bid >> 5;              // 0..31, dispatch order
  const int bh = bid & 31;
  const int b = bh >> 4;
  const int h = bh & 15;
  const int q32 = 31 - j;              // longest-first: q32=31 (64 tiles) goes first
  const int qb = q32 * 64;
  const int tok0 = b * S_LEN;

  const int tid = threadIdx.x;
  const int lane = tid & 63;
  const int wave = tid >> 6;
  const int m16 = lane & 15;
  const int quad = lane >> 4;
  const int R0 = qb + wave * 16;       // this wave's first q-row

  auto stageKV = [&](int buf, int kbase) {
#pragma unroll
    for (int jj = 0; jj < 3; ++jj) {
      const int i = wave * 3 + jj;            // instr 0..11
      const int ch = i * 2 + (lane >> 5);     // wave-uniform side of 16
      const int key = lane & 31;
      const _Float16* g = (ch < 16)
          ? kn + (size_t)(tok0 + kbase + key) * 2048 + h * 128 + ch * 8
          : kr + (size_t)(tok0 + kbase + key) * 64 + (ch - 16) * 8;
      async16(g, &Ks[buf][i * 512]);
    }
#pragma unroll
    for (int jj = 0; jj < 2; ++jj) {
      const int i = wave * 2 + jj;            // instr 0..7
      const int p = i * 64 + lane;            // LDS chunk position 0..511
      const int L = p ^ ((p >> 3) & 3);       // involutive source pre-swizzle
      const int dv = L >> 2;
      const int qc = L & 3;
      async16(vT + (size_t)(h * 128 + dv) * TOKENS + tok0 + kbase + qc * 8,
              &Vs[buf][i * 512]);
    }
  };

  const float scale2 = 0.07216878364870323f * 1.4426950408889634f;  // /sqrt(192), log2 dom
  const fx4 fz = {0.f, 0.f, 0.f, 0.f};

  // ---- Q fragments (A-layout), loaded once ----
  f16x8 qf[6];
  {
    const size_t t = (size_t)(tok0 + qb + wave * 16 + m16);
#pragma unroll
    for (int kk = 0; kk < 4; ++kk)
      qf[kk] = *(const f16x8*)(qn + t * 2048 + h * 128 + kk * 32 + quad * 8);
#pragma unroll
    for (int kk = 0; kk < 2; ++kk)
      qf[4 + kk] = *(const f16x8*)(qp + t * 1024 + h * 64 + kk * 32 + quad * 8);
  }

  fx4 oacc[8];
#pragma unroll
  for (int n = 0; n < 8; ++n) oacc[n] = fz;
  float mst[4], lst[4];
#pragma unroll
  for (int r = 0; r < 4; ++r) { mst[r] = -3.0e38f; lst[r] = 0.f; }

  const int nkt = (qb >> 5) + 2;       // key tiles: 0 .. qb+63 (2..64)

  stageKV(0, 0);
  for (int kt = 0; kt < nkt; ++kt) {
    const int kbase = kt * 32;
    __syncthreads();                   // buf[kt&1] ready (drains in-flight stage)
    if (kt + 1 < nkt) stageKV((kt + 1) & 1, kbase + 32);

    const bool live = (kbase <= R0 + 15);
    if (!live) continue;               // fully-masked tile for this wave
    const _Float16* ks = Ks[kt & 1];
    const _Float16* vs = Vs[kt & 1];

    // ---- S = Q K^T : 2 key-groups x 6 kk ----
    fx4 sc[2];
    sc[0] = fz; sc[1] = fz;
    __builtin_amdgcn_s_setprio(1);
#pragma unroll
    for (int kk = 0; kk < 6; ++kk) {
#pragma unroll
      for (int n = 0; n < 2; ++n) {
        f16x8 kf = *(const f16x8*)(&ks[(kk * 128 + quad * 32 + n * 16 + m16) * 8]);
        sc[n] = __builtin_amdgcn_mfma_f32_16x16x32_f16(qf[kk], kf, sc[n], 0, 0, 0);
      }
    }
    __builtin_amdgcn_s_setprio(0);

    // V fragments from LDS (B-layout), swizzled read: issued now, used at PV
    f16x8 vf[8];
#pragma unroll
    for (int n8 = 0; n8 < 8; ++n8) {
      const int c0 = (n8 * 16 + m16) * 4 + quad;
      vf[n8] = *(const f16x8*)(&vs[(c0 ^ ((c0 >> 3) & 3)) * 8]);
    }

    // ---- online softmax, log2 dom, DPP reduce (row=quad*4+r, col=n*16+m16) ----
    const bool needmask = (kbase + 31 > R0);
    float alpha[4];
    bool any_upd = false;
#pragma unroll
    for (int r = 0; r < 4; ++r) {
      float v0 = sc[0][r] * scale2;
      float v1 = sc[1][r] * scale2;
      if (needmask) {
        const int qrow = R0 + quad * 4 + r;
        if (kbase + m16 > qrow)      v0 = -3.0e38f;
        if (kbase + 16 + m16 > qrow) v1 = -3.0e38f;
      }
      float mx = fmaxf(v0, v1);
      mx = fmaxf(mx, ROR16(mx, 0x128));
      mx = fmaxf(mx, ROR16(mx, 0x124));
      mx = fmaxf(mx, ROR16(mx, 0x122));
      mx = fmaxf(mx, ROR16(mx, 0x121));
      float al = 1.0f;
      if (__any(mx > mst[r] + 10.0f)) {     // defer-max: only rescale on real growth
        const float mn = fmaxf(mst[r], mx);
        al = exp2f(mst[r] - mn);
        mst[r] = mn;
        any_upd = true;
      }
      alpha[r] = al;
      const float p0 = exp2f(v0 - mst[r]);
      const float p1 = exp2f(v1 - mst[r]);
      float ls = p0 + p1;
      ls += ROR16(ls, 0x128);
      ls += ROR16(ls, 0x124);
      ls += ROR16(ls, 0x122);
      ls += ROR16(ls, 0x121);
      lst[r] = lst[r] * al + ls;
      _Float16* pr = &Ps[wave][quad * 4 + r][0];
      pr[m16] = (_Float16)p0;
      pr[16 + m16] = (_Float16)p1;
    }
    if (any_upd) {
#pragma unroll
      for (int n8 = 0; n8 < 8; ++n8)
#pragma unroll
        for (int r = 0; r < 4; ++r) oacc[n8][r] *= alpha[r];
    }

    // ---- O += P V  (P via wave-private LDS -> A-layout; V from regs) ----
    f16x8 pf = *(const f16x8*)(&Ps[wave][m16][quad * 8]);
    __builtin_amdgcn_s_setprio(1);
#pragma unroll
    for (int n8 = 0; n8 < 8; ++n8)
      oacc[n8] = __builtin_amdgcn_mfma_f32_16x16x32_f16(pf, vf[n8], oacc[n8], 0, 0, 0);
    __builtin_amdgcn_s_setprio(0);
  }

  // ---- epilogue ----
  float inv[4];
#pragma unroll
  for (int r = 0; r < 4; ++r) inv[r] = 1.0f / lst[r];
#pragma unroll
  for (int n8 = 0; n8 < 8; ++n8) {
#pragma unroll
    for (int r = 0; r < 4; ++r) {
      const size_t t = (size_t)(tok0 + qb + wave * 16 + quad * 4 + r);
      out[t * 2048 + h * 128 + n8 * 16 + m16] = (_Float16)(oacc[n8][r] * inv[r]);
    }
  }
}

// ---------------- launch ----------------------------------------------------
extern "C" void kernel_launch(void* const* d_in, const int* in_sizes, int n_in,
                              void* d_out, int out_size, void* d_ws, size_t ws_size,
                              hipStream_t stream) {
  const float* x         = (const float*)d_in[0];
  const float* wq_down   = (const float*)d_in[1];
  const float* q_norm_w  = (const float*)d_in[2];
  const float* wq_up     = (const float*)d_in[3];
  const float* wq_rope   = (const float*)d_in[4];
  const float* wkv_down  = (const float*)d_in[5];
  const float* kv_norm_w = (const float*)d_in[6];
  const float* wkv_up    = (const float*)d_in[7];
  const float* wk_rope   = (const float*)d_in[8];
  const float* wo        = (const float*)d_in[9];
  float* out = (float*)d_out;

  char* ws = (char*)d_ws;
  size_t off = 0;
  auto alloc = [&](size_t bytes) {
    char* p = ws + off;
    off += (bytes + 255) & ~(size_t)255;
    return p;
  };
  _Float16* x_h     = (_Float16*)alloc((size_t)TOKENS * DIM * 2);
  _Float16* wqd_h   = (_Float16*)alloc((size_t)QR * DIM * 2);
  _Float16* wquqr_h = (_Float16*)alloc((size_t)3072 * QR * 2);       // wq_up | wq_rope
  _Float16* wkvdr_h = (_Float16*)alloc((size_t)576 * DIM * 2);       // wkv_down | wk_rope
  _Float16* wkvu_h  = (_Float16*)alloc((size_t)NH * 256 * KVR * 2);
  _Float16* wo_h    = (_Float16*)alloc((size_t)DIM * NH * DV * 2);
  _Float16* qc_h    = (_Float16*)alloc((size_t)TOKENS * QR * 2);
  _Float16* kvc_h   = (_Float16*)alloc((size_t)TOKENS * KVR * 2);
  _Float16* qnope_h = (_Float16*)alloc((size_t)TOKENS * 2048 * 2);
  _Float16* qpe_h   = (_Float16*)alloc((size_t)TOKENS * 1024 * 2);
  _Float16* knope_h = (_Float16*)alloc((size_t)TOKENS * 2048 * 2);
  _Float16* vT_h    = (_Float16*)alloc((size_t)2048 * TOKENS * 2);
  _Float16* krope_h = (_Float16*)alloc((size_t)TOKENS * DR * 2);
  _Float16* attn_h  = (_Float16*)alloc((size_t)TOKENS * 2048 * 2);

  // ---- one fused conversion dispatch ----
  CvtSegs cs;
  const float* srcs[8] = {x, wq_down, wq_up, wq_rope, wkv_down, wk_rope, wkv_up, wo};
  _Float16* dsts[8] = {x_h, wqd_h, wquqr_h, wquqr_h + (size_t)2048 * QR,
                       wkvdr_h, wkvdr_h + (size_t)512 * DIM, wkvu_h, wo_h};
  const size_t ns[8] = {(size_t)TOKENS * DIM, (size_t)QR * DIM, (size_t)2048 * QR,
                        (size_t)1024 * QR, (size_t)KVR * DIM, (size_t)DR * DIM,
                        (size_t)NH * 256 * KVR, (size_t)DIM * NH * DV};
  int cum = 0;
  for (int i = 0; i < 8; ++i) {
    cs.src[i] = srcs[i];
    cs.dst[i] = dsts[i];
    cs.n4[i] = (int)(ns[i] / 4);
    cs.cum[i] = cum;
    cum += (cs.n4[i] + 255) / 256;
  }
  cs.cum[8] = cum;
  cvt_all<<<dim3(cum), 256, 0, stream>>>(cs);

  auto gx = [](int n) { return (unsigned)((n + 127) / 128); };
  const unsigned gm = TOKENS / 128;

  // q path: x -> qc (N=1536)
  gemm_nt<0><<<dim3(gx(QR), gm), 256, 0, stream>>>(x_h, wqd_h, qc_h, nullptr, TOKENS, QR, DIM);
  rmsnorm_ip<QR><<<dim3(TOKENS), 256, 0, stream>>>(qc_h, q_norm_w);
  // kv path fused with rope-key: x -> kvc | krope (N=576)
  gemm_nt<4><<<dim3(gx(576), gm), 256, 0, stream>>>(x_h, wkvdr_h, kvc_h, krope_h, TOKENS, 576, DIM);
  rmsnorm_ip<KVR><<<dim3(TOKENS), 256, 0, stream>>>(kvc_h, kv_norm_w);
  rope_k<<<dim3(TOKENS * 32 / 256), 256, 0, stream>>>(krope_h);
  // q up fused: qc -> qnope | qpe (N=3072)
  gemm_nt<3><<<dim3(gx(3072), gm), 256, 0, stream>>>(qc_h, wquqr_h, qnope_h, qpe_h, TOKENS, 3072, QR);
  rope_q<<<dim3(TOKENS * NH * 32 / 256), 256, 0, stream>>>(qpe_h);
  // kv up-projection, split epilogue: k_nope natural + V transposed
  gemm_nt<2><<<dim3(gx(4096), gm), 256, 0, stream>>>(kvc_h, wkvu_h, knope_h, vT_h, TOKENS, 4096, KVR);
  // attention: 1024 blocks (one 64-row q-tile each), longest-first dispatch
  mla_attn<<<dim3(1024), 256, 0, stream>>>(qnope_h, qpe_h, knope_h, krope_h, vT_h, attn_h);
  // output projection (fp32 out)
  gemm_nt<1><<<dim3(gx(DIM), gm), 256, 0, stream>>>(attn_h, wo_h, out, nullptr, TOKENS, DIM, NH * DV);
}

// Round 6
// 475.807 us; speedup vs baseline: 1.1192x; 1.0768x over previous
//
#include <hip/hip_runtime.h>
#include <stdint.h>

typedef _Float16 f16x8 __attribute__((ext_vector_type(8)));
typedef _Float16 f16x4 __attribute__((ext_vector_type(4)));
typedef float fx4 __attribute__((ext_vector_type(4)));

static constexpr int S_LEN = 2048;
static constexpr int BATCH = 2;
static constexpr int TOKENS = BATCH * S_LEN;   // 4096
static constexpr int DIM = 2048;
static constexpr int NH = 16;
static constexpr int QR = 1536;
static constexpr int KVR = 512;
static constexpr int DN = 128;
static constexpr int DR = 64;
static constexpr int DV = 128;

// async global->LDS, 16B per lane; LDS dest = wave-uniform base, HW adds lane*16
__device__ __forceinline__ void async16(const _Float16* g, _Float16* lds_base_uniform) {
  __builtin_amdgcn_global_load_lds(
      (const __attribute__((address_space(1))) void*)g,
      (__attribute__((address_space(3))) void*)lds_base_uniform, 16, 0, 0);
}

// raw barrier WITHOUT the implicit vmcnt(0) drain of __syncthreads
__device__ __forceinline__ void bar() {
  asm volatile("" ::: "memory");
  __builtin_amdgcn_s_barrier();
  asm volatile("" ::: "memory");
}
#define VMWAIT(n) asm volatile("s_waitcnt vmcnt(" #n ")" ::: "memory")

// intra-16-lane rotate via DPP (VALU, ~4cyc vs ~35cyc ds_swizzle)
#define ROR16(x, ctrl) \
  __uint_as_float(__builtin_amdgcn_update_dpp(__float_as_uint(x), __float_as_uint(x), \
                                              (ctrl), 0xF, 0xF, false))

// sin/cos via v_sin/v_cos (input = revolutions), manual range reduction
__device__ __forceinline__ void sincos_rev(float ang, float* sn, float* cs) {
  float rev = ang * 0.15915494309189535f;
  rev -= floorf(rev);
  *sn = __builtin_amdgcn_sinf(rev);   // sin(2*pi*rev)
  *cs = __builtin_amdgcn_cosf(rev);
}

// ---------------- fused f32 -> f16 conversion (all tensors, one dispatch) ---
struct CvtSegs {
  const float* src[8];
  _Float16* dst[8];
  int n4[8];
  int cum[9];
};
__global__ __launch_bounds__(256) void cvt_all(CvtSegs s) {
  const int b = blockIdx.x;
  int seg = 0;
#pragma unroll
  for (int k = 0; k < 7; ++k) seg += (b >= s.cum[seg + 1]) ? 1 : 0;
  const int i = (b - s.cum[seg]) * 256 + threadIdx.x;
  if (i >= s.n4[seg]) return;
  fx4 v = *(const fx4*)(s.src[seg] + (size_t)i * 4);
  f16x4 o;
  o[0] = (_Float16)v[0]; o[1] = (_Float16)v[1];
  o[2] = (_Float16)v[2]; o[3] = (_Float16)v[3];
  *(f16x4*)(s.dst[seg] + (size_t)i * 4) = o;
}

// ---------------- NT GEMM, 3-buffer LDS, counted vmcnt (no drain) ----------
// C[M,N] = A[M,K] * W[N,K]^T.  128x128 tile, BK=32.
// MODE 1: f32 C0 (out-proj).
// MODE 5: down-proj split: col<1536 -> qc[.,1536]; <2048 -> kvc[.,512];
//         <2112 -> krope[.,64].  (weights stacked wq_down|wkv_down|wk_rope)
template <int MODE>
__global__ __launch_bounds__(256) void gemm_nt(const _Float16* __restrict__ A,
                                               const _Float16* __restrict__ W,
                                               void* __restrict__ C0v,
                                               void* __restrict__ C1v,
                                               void* __restrict__ C2v,
                                               int M, int N, int K) {
  __shared__ __attribute__((aligned(16))) _Float16 As[3][128 * 32];
  __shared__ __attribute__((aligned(16))) _Float16 Ws[3][128 * 32];
  const int tid = threadIdx.x;
  const int lane = tid & 63;
  const int wave = tid >> 6;
  const int wr = (wave >> 1) * 64;
  const int wc = (wave & 1) * 64;
  const int m16 = lane & 15;
  const int quad = lane >> 4;
  const int m0 = blockIdx.y * 128;
  const int n0 = blockIdx.x * 128;

  auto stage = [&](int buf, int k0) {
#pragma unroll
    for (int p = 0; p < 2; ++p) {
      const int cb = p * 256 + wave * 64;   // wave-uniform chunk base
      const int ch = cb + lane;
      const int r = ch >> 2;
      const int c8 = (ch & 3) * 8;
      async16(A + (size_t)(m0 + r) * K + k0 + c8, &As[buf][cb * 8]);
      async16(W + (size_t)(n0 + r) * K + k0 + c8, &Ws[buf][cb * 8]);
    }
  };

  const fx4 fz = {0.f, 0.f, 0.f, 0.f};
  fx4 acc[4][4];
#pragma unroll
  for (int i = 0; i < 4; ++i)
#pragma unroll
    for (int j = 0; j < 4; ++j) acc[i][j] = fz;

  const int nkt = K >> 5;
  stage(0, 0);
  stage(1, 32);
  int cur = 0;
  for (int kt = 0; kt < nkt; ++kt) {
    if (kt + 1 < nkt) { VMWAIT(4); } else { VMWAIT(0); }
    bar();
    if (kt + 2 < nkt) {
      int b2 = cur + 2; if (b2 >= 3) b2 -= 3;
      stage(b2, (kt + 2) * 32);
    }
    const _Float16* as = As[cur];
    const _Float16* ws = Ws[cur];
    f16x8 af[4], wf[4];
#pragma unroll
    for (int i = 0; i < 4; ++i)
      af[i] = *(const f16x8*)(&as[(wr + i * 16 + m16) * 32 + quad * 8]);
#pragma unroll
    for (int j = 0; j < 4; ++j)
      wf[j] = *(const f16x8*)(&ws[(wc + j * 16 + m16) * 32 + quad * 8]);
#pragma unroll
    for (int i = 0; i < 4; ++i)
#pragma unroll
      for (int j = 0; j < 4; ++j)
        acc[i][j] = __builtin_amdgcn_mfma_f32_16x16x32_f16(af[i], wf[j], acc[i][j], 0, 0, 0);
    if (++cur == 3) cur = 0;
  }

#pragma unroll
  for (int j = 0; j < 4; ++j) {
    const int col = n0 + wc + j * 16 + m16;
    if (MODE == 5) {
#pragma unroll
      for (int i = 0; i < 4; ++i)
#pragma unroll
        for (int r = 0; r < 4; ++r) {
          const size_t row = (size_t)(m0 + wr + i * 16 + quad * 4 + r);
          const _Float16 v = (_Float16)acc[i][j][r];
          if (col < 1536)      ((_Float16*)C0v)[row * 1536 + col] = v;
          else if (col < 2048) ((_Float16*)C1v)[row * 512 + col - 1536] = v;
          else if (col < 2112) ((_Float16*)C2v)[row * 64 + col - 2048] = v;
        }
    } else {
      if (col < N) {
#pragma unroll
        for (int i = 0; i < 4; ++i)
#pragma unroll
          for (int r = 0; r < 4; ++r) {
            const size_t row = (size_t)(m0 + wr + i * 16 + quad * 4 + r);
            ((float*)C0v)[row * N + col] = acc[i][j][r];
          }
      }
    }
  }
}

// ---------------- fused up-projections: q-up + kv-up in one dispatch -------
// blockIdx.x < 24: qc[4096,1536] x wquqr[3072,1536]^T -> qnope|qpe
// else           : kvc[4096,512] x wkvu[4096,512]^T   -> knope + vT (transposed)
__global__ __launch_bounds__(256) void gemm_up(
    const _Float16* __restrict__ qc, const _Float16* __restrict__ wqu,
    const _Float16* __restrict__ kvc, const _Float16* __restrict__ wkvu,
    _Float16* __restrict__ qnope, _Float16* __restrict__ qpe,
    _Float16* __restrict__ knope, _Float16* __restrict__ vT) {
  __shared__ __attribute__((aligned(16))) _Float16 As[3][128 * 32];
  __shared__ __attribute__((aligned(16))) _Float16 Ws[3][128 * 32];
  const int tid = threadIdx.x;
  const int lane = tid & 63;
  const int wave = tid >> 6;
  const int wr = (wave >> 1) * 64;
  const int wc = (wave & 1) * 64;
  const int m16 = lane & 15;
  const int quad = lane >> 4;
  const int m0 = blockIdx.y * 128;
  const bool isq = (blockIdx.x < 24);
  const int n0 = (isq ? blockIdx.x : blockIdx.x - 24) * 128;
  const _Float16* A = isq ? qc : kvc;
  const _Float16* W = isq ? wqu : wkvu;
  const int K = isq ? QR : KVR;

  auto stage = [&](int buf, int k0) {
#pragma unroll
    for (int p = 0; p < 2; ++p) {
      const int cb = p * 256 + wave * 64;
      const int ch = cb + lane;
      const int r = ch >> 2;
      const int c8 = (ch & 3) * 8;
      async16(A + (size_t)(m0 + r) * K + k0 + c8, &As[buf][cb * 8]);
      async16(W + (size_t)(n0 + r) * K + k0 + c8, &Ws[buf][cb * 8]);
    }
  };

  const fx4 fz = {0.f, 0.f, 0.f, 0.f};
  fx4 acc[4][4];
#pragma unroll
  for (int i = 0; i < 4; ++i)
#pragma unroll
    for (int j = 0; j < 4; ++j) acc[i][j] = fz;

  const int nkt = K >> 5;                  // 48 or 16
  stage(0, 0);
  stage(1, 32);
  int cur = 0;
  for (int kt = 0; kt < nkt; ++kt) {
    if (kt + 1 < nkt) { VMWAIT(4); } else { VMWAIT(0); }
    bar();
    if (kt + 2 < nkt) {
      int b2 = cur + 2; if (b2 >= 3) b2 -= 3;
      stage(b2, (kt + 2) * 32);
    }
    const _Float16* as = As[cur];
    const _Float16* ws = Ws[cur];
    f16x8 af[4], wf[4];
#pragma unroll
    for (int i = 0; i < 4; ++i)
      af[i] = *(const f16x8*)(&as[(wr + i * 16 + m16) * 32 + quad * 8]);
#pragma unroll
    for (int j = 0; j < 4; ++j)
      wf[j] = *(const f16x8*)(&ws[(wc + j * 16 + m16) * 32 + quad * 8]);
#pragma unroll
    for (int i = 0; i < 4; ++i)
#pragma unroll
      for (int j = 0; j < 4; ++j)
        acc[i][j] = __builtin_amdgcn_mfma_f32_16x16x32_f16(af[i], wf[j], acc[i][j], 0, 0, 0);
    if (++cur == 3) cur = 0;
  }

#pragma unroll
  for (int j = 0; j < 4; ++j) {
    const int col = n0 + wc + j * 16 + m16;
    if (isq) {
      // q-up: col<2048 -> qnope[.,2048], else qpe[.,1024]
#pragma unroll
      for (int i = 0; i < 4; ++i)
#pragma unroll
        for (int r = 0; r < 4; ++r) {
          const size_t row = (size_t)(m0 + wr + i * 16 + quad * 4 + r);
          if (col < 2048) qnope[row * 2048 + col] = (_Float16)acc[i][j][r];
          else qpe[row * 1024 + col - 2048] = (_Float16)acc[i][j][r];
        }
    } else {
      // kv-up: sub<128 -> knope natural; else vT transposed
      const int head = col >> 8;
      const int sub = col & 255;
      if (sub < 128) {
#pragma unroll
        for (int i = 0; i < 4; ++i)
#pragma unroll
          for (int r = 0; r < 4; ++r)
            knope[(size_t)(m0 + wr + i * 16 + quad * 4 + r) * 2048 + head * 128 + sub] =
                (_Float16)acc[i][j][r];
      } else {
        const int dv = sub - 128;
#pragma unroll
        for (int i = 0; i < 4; ++i) {
          f16x4 v;
#pragma unroll
          for (int r = 0; r < 4; ++r) v[r] = (_Float16)acc[i][j][r];
          *(f16x4*)(&vT[(size_t)(head * 128 + dv) * TOKENS + m0 + wr + i * 16 + quad * 4]) = v;
        }
      }
    }
  }
}

// ---------------- fused: RMSNorm(qc) + RMSNorm(kvc) + rope_k ---------------
__global__ __launch_bounds__(256) void rms_rope(_Float16* __restrict__ qc,
                                                const float* __restrict__ qw,
                                                _Float16* __restrict__ kvc,
                                                const float* __restrict__ kvw,
                                                _Float16* __restrict__ kr) {
  const int bid = blockIdx.x;
  if (bid < 2 * TOKENS) {
    const bool isq = bid < TOKENS;
    const int row = isq ? bid : bid - TOKENS;
    const int NC = isq ? QR : KVR;
    _Float16* p = (isq ? qc : kvc) + (size_t)row * NC;
    const float* w = isq ? qw : kvw;
    float ss = 0.f;
    for (int c = threadIdx.x; c < NC; c += 256) {
      const float v = (float)p[c];
      ss += v * v;
    }
#pragma unroll
    for (int d = 1; d < 64; d <<= 1) ss += __shfl_xor(ss, d);
    __shared__ float red[4];
    if ((threadIdx.x & 63) == 0) red[threadIdx.x >> 6] = ss;
    __syncthreads();
    const float rs = rsqrtf((red[0] + red[1] + red[2] + red[3]) / (float)NC + 1e-6f);
    for (int c = threadIdx.x; c < NC; c += 256)
      p[c] = (_Float16)((float)p[c] * rs * w[c]);
  } else {
    // rope_k: [T,64], T*32 threads
    const int idx = (bid - 2 * TOKENS) * 256 + threadIdx.x;
    const int t = idx >> 5;
    const int i = idx & 31;
    const int s = t & (S_LEN - 1);
    const float fr = exp2f(-(float)i * 0.4152410118609203f);  // log2(1e4)/32
    const float ang = (float)s * fr;
    float sn, cs;
    sincos_rev(ang, &sn, &cs);
    const size_t base = (size_t)t * DR + 2 * i;
    const float x1 = (float)kr[base];
    const float x2 = (float)kr[base + 1];
    kr[base] = (_Float16)(x1 * cs - x2 * sn);
    kr[base + 1] = (_Float16)(x1 * sn + x2 * cs);
  }
}

// ---------------- causal flash attention v8 --------------------------------
// v7 structure (one 64-row q-tile/block, longest-first, 2-buffer KV in LDS,
// DPP softmax, defer-max) plus:
//  - RoPE applied to Q fragments at load (rope_q dispatch deleted)
//  - l-sum via ones-column MFMA (oacc[8]); sum DPP chain deleted
//  - max DPP chain only when __any detects growth (rare) -> ~70 VALU/tile cut
__global__ __launch_bounds__(256, 2) void mla_attn(
    const _Float16* __restrict__ qn,   // [T, NH*128]
    const _Float16* __restrict__ qp,   // [T, NH*64]  RAW (rope applied here)
    const _Float16* __restrict__ kn,   // [T, NH*128]
    const _Float16* __restrict__ kr,   // [T, 64]     roped
    const _Float16* __restrict__ vT,   // [NH*128, T]
    _Float16* __restrict__ out)        // [T, NH*128]
{
  __shared__ __attribute__((aligned(16))) _Float16 Ks[2][768 * 8];  // 24 KB
  __shared__ __attribute__((aligned(16))) _Float16 Vs[2][512 * 8];  // 16 KB
  __shared__ __attribute__((aligned(16))) _Float16 Ps[4][16][40];   // 5 KB

  const int bid = blockIdx.x;          // 1024 = 32 q-tiles (longest first) x 32 (b,h)
  const int j = bid >> 5;
  const int bh = bid & 31;
  const int b = bh >> 4;
  const int h = bh & 15;
  const int q32 = 31 - j;              // longest-first
  const int qb = q32 * 64;
  const int tok0 = b * S_LEN;

  const int tid = threadIdx.x;
  const int lane = tid & 63;
  const int wave = tid >> 6;
  const int m16 = lane & 15;
  const int quad = lane >> 4;
  const int R0 = qb + wave * 16;

  auto stageKV = [&](int buf, int kbase) {
#pragma unroll
    for (int jj = 0; jj < 3; ++jj) {
      const int i = wave * 3 + jj;
      const int ch = i * 2 + (lane >> 5);
      const int key = lane & 31;
      const _Float16* g = (ch < 16)
          ? kn + (size_t)(tok0 + kbase + key) * 2048 + h * 128 + ch * 8
          : kr + (size_t)(tok0 + kbase + key) * 64 + (ch - 16) * 8;
      async16(g, &Ks[buf][i * 512]);
    }
#pragma unroll
    for (int jj = 0; jj < 2; ++jj) {
      const int i = wave * 2 + jj;
      const int p = i * 64 + lane;
      const int L = p ^ ((p >> 3) & 3);       // involutive source pre-swizzle
      const int dv = L >> 2;
      const int qc = L & 3;
      async16(vT + (size_t)(h * 128 + dv) * TOKENS + tok0 + kbase + qc * 8,
              &Vs[buf][i * 512]);
    }
  };

  const float scale2 = 0.07216878364870323f * 1.4426950408889634f;  // /sqrt(192), log2 dom
  const fx4 fz = {0.f, 0.f, 0.f, 0.f};

  // ---- Q fragments (A-layout); RoPE applied to the qp fragments in-reg ----
  f16x8 qf[6];
  {
    const int srow = qb + wave * 16 + m16;     // seq position (0..2047)
    const size_t t = (size_t)(tok0 + srow);
#pragma unroll
    for (int kk = 0; kk < 4; ++kk)
      qf[kk] = *(const f16x8*)(qn + t * 2048 + h * 128 + kk * 32 + quad * 8);
#pragma unroll
    for (int kk = 0; kk < 2; ++kk) {
      f16x8 v = *(const f16x8*)(qp + t * 1024 + h * 64 + kk * 32 + quad * 8);
      f16x8 o;
      const int i0 = kk * 16 + quad * 4;       // rope pair index base
#pragma unroll
      for (int jj = 0; jj < 4; ++jj) {
        const float ang = (float)srow * exp2f(-(float)(i0 + jj) * 0.4152410118609203f);
        float sn, cs;
        sincos_rev(ang, &sn, &cs);
        const float x1 = (float)v[2 * jj], x2 = (float)v[2 * jj + 1];
        o[2 * jj]     = (_Float16)(x1 * cs - x2 * sn);
        o[2 * jj + 1] = (_Float16)(x1 * sn + x2 * cs);
      }
      qf[4 + kk] = o;
    }
  }

  fx4 oacc[9];                         // [8] accumulates row-sums (P x ones)
#pragma unroll
  for (int n = 0; n < 9; ++n) oacc[n] = fz;
  float mst[4];
#pragma unroll
  for (int r = 0; r < 4; ++r) mst[r] = -3.0e38f;
  f16x8 vones;
#pragma unroll
  for (int e = 0; e < 8; ++e) vones[e] = (_Float16)1.0f;

  const int nkt = (qb >> 5) + 2;

  stageKV(0, 0);
  for (int kt = 0; kt < nkt; ++kt) {
    const int kbase = kt * 32;
    __syncthreads();
    if (kt + 1 < nkt) stageKV((kt + 1) & 1, kbase + 32);

    const bool live = (kbase <= R0 + 15);
    if (!live) continue;
    const _Float16* ks = Ks[kt & 1];
    const _Float16* vs = Vs[kt & 1];

    // ---- S = Q K^T ----
    fx4 sc[2];
    sc[0] = fz; sc[1] = fz;
    __builtin_amdgcn_s_setprio(1);
#pragma unroll
    for (int kk = 0; kk < 6; ++kk) {
#pragma unroll
      for (int n = 0; n < 2; ++n) {
        f16x8 kf = *(const f16x8*)(&ks[(kk * 128 + quad * 32 + n * 16 + m16) * 8]);
        sc[n] = __builtin_amdgcn_mfma_f32_16x16x32_f16(qf[kk], kf, sc[n], 0, 0, 0);
      }
    }
    __builtin_amdgcn_s_setprio(0);

    // V fragments from LDS (swizzled read)
    f16x8 vf[8];
#pragma unroll
    for (int n8 = 0; n8 < 8; ++n8) {
      const int c0 = (n8 * 16 + m16) * 4 + quad;
      vf[n8] = *(const f16x8*)(&vs[(c0 ^ ((c0 >> 3) & 3)) * 8]);
    }

    // ---- online softmax: max-reduce only on growth; no sum-reduce at all ----
    const bool needmask = (kbase + 31 > R0);
    float alpha[4];
    bool any_upd = false;
#pragma unroll
    for (int r = 0; r < 4; ++r) {
      float v0 = sc[0][r] * scale2;
      float v1 = sc[1][r] * scale2;
      if (needmask) {
        const int qrow = R0 + quad * 4 + r;
        if (kbase + m16 > qrow)      v0 = -3.0e38f;
        if (kbase + 16 + m16 > qrow) v1 = -3.0e38f;
      }
      const float pre = fmaxf(v0, v1);
      float al = 1.0f;
      if (__any(pre > mst[r] + 10.0f)) {       // rare after warm-up
        float mx = pre;
        mx = fmaxf(mx, ROR16(mx, 0x128));
        mx = fmaxf(mx, ROR16(mx, 0x124));
        mx = fmaxf(mx, ROR16(mx, 0x122));
        mx = fmaxf(mx, ROR16(mx, 0x121));
        const float mn = fmaxf(mst[r], mx);
        al = exp2f(mst[r] - mn);
        mst[r] = mn;
        any_upd = true;
      }
      alpha[r] = al;
      const float p0 = exp2f(v0 - mst[r]);
      const float p1 = exp2f(v1 - mst[r]);
      _Float16* pr = &Ps[wave][quad * 4 + r][0];
      pr[m16] = (_Float16)p0;
      pr[16 + m16] = (_Float16)p1;
    }
    if (any_upd) {
#pragma unroll
      for (int n8 = 0; n8 < 9; ++n8)
#pragma unroll
        for (int r = 0; r < 4; ++r) oacc[n8][r] *= alpha[r];
    }

    // ---- O += P V ; row-sums accumulate via ones-column MFMA ----
    f16x8 pf = *(const f16x8*)(&Ps[wave][m16][quad * 8]);
    __builtin_amdgcn_s_setprio(1);
#pragma unroll
    for (int n8 = 0; n8 < 8; ++n8)
      oacc[n8] = __builtin_amdgcn_mfma_f32_16x16x32_f16(pf, vf[n8], oacc[n8], 0, 0, 0);
    oacc[8] = __builtin_amdgcn_mfma_f32_16x16x32_f16(pf, vones, oacc[8], 0, 0, 0);
    __builtin_amdgcn_s_setprio(0);
  }

  // ---- epilogue: normalize by oacc[8] (row sums; all cols equal) ----
  float inv[4];
#pragma unroll
  for (int r = 0; r < 4; ++r) inv[r] = 1.0f / oacc[8][r];
#pragma unroll
  for (int n8 = 0; n8 < 8; ++n8) {
#pragma unroll
    for (int r = 0; r < 4; ++r) {
      const size_t t = (size_t)(tok0 + qb + wave * 16 + quad * 4 + r);
      out[t * 2048 + h * 128 + n8 * 16 + m16] = (_Float16)(oacc[n8][r] * inv[r]);
    }
  }
}

// ---------------- launch ----------------------------------------------------
extern "C" void kernel_launch(void* const* d_in, const int* in_sizes, int n_in,
                              void* d_out, int out_size, void* d_ws, size_t ws_size,
                              hipStream_t stream) {
  const float* x         = (const float*)d_in[0];
  const float* wq_down   = (const float*)d_in[1];
  const float* q_norm_w  = (const float*)d_in[2];
  const float* wq_up     = (const float*)d_in[3];
  const float* wq_rope   = (const float*)d_in[4];
  const float* wkv_down  = (const float*)d_in[5];
  const float* kv_norm_w = (const float*)d_in[6];
  const float* wkv_up    = (const float*)d_in[7];
  const float* wk_rope   = (const float*)d_in[8];
  const float* wo        = (const float*)d_in[9];
  float* out = (float*)d_out;

  char* ws = (char*)d_ws;
  size_t off = 0;
  auto alloc = [&](size_t bytes) {
    char* p = ws + off;
    off += (bytes + 255) & ~(size_t)255;
    return p;
  };
  _Float16* x_h     = (_Float16*)alloc((size_t)TOKENS * DIM * 2);
  _Float16* wA_h    = (_Float16*)alloc((size_t)2176 * DIM * 2);      // wq_down|wkv_down|wk_rope (+pad)
  _Float16* wquqr_h = (_Float16*)alloc((size_t)3072 * QR * 2);       // wq_up | wq_rope
  _Float16* wkvu_h  = (_Float16*)alloc((size_t)NH * 256 * KVR * 2);
  _Float16* wo_h    = (_Float16*)alloc((size_t)DIM * NH * DV * 2);
  _Float16* qc_h    = (_Float16*)alloc((size_t)TOKENS * QR * 2);
  _Float16* kvc_h   = (_Float16*)alloc((size_t)TOKENS * KVR * 2);
  _Float16* qnope_h = (_Float16*)alloc((size_t)TOKENS * 2048 * 2);
  _Float16* qpe_h   = (_Float16*)alloc((size_t)TOKENS * 1024 * 2);
  _Float16* knope_h = (_Float16*)alloc((size_t)TOKENS * 2048 * 2);
  _Float16* vT_h    = (_Float16*)alloc((size_t)2048 * TOKENS * 2);
  _Float16* krope_h = (_Float16*)alloc((size_t)TOKENS * DR * 2);
  _Float16* attn_h  = (_Float16*)alloc((size_t)TOKENS * 2048 * 2);

  // ---- one fused conversion dispatch ----
  CvtSegs cs;
  const float* srcs[8] = {x, wq_down, wq_up, wq_rope, wkv_down, wk_rope, wkv_up, wo};
  _Float16* dsts[8] = {x_h, wA_h, wquqr_h, wquqr_h + (size_t)2048 * QR,
                       wA_h + (size_t)1536 * DIM, wA_h + (size_t)2048 * DIM,
                       wkvu_h, wo_h};
  const size_t ns[8] = {(size_t)TOKENS * DIM, (size_t)QR * DIM, (size_t)2048 * QR,
                        (size_t)1024 * QR, (size_t)KVR * DIM, (size_t)DR * DIM,
                        (size_t)NH * 256 * KVR, (size_t)DIM * NH * DV};
  int cum = 0;
  for (int i = 0; i < 8; ++i) {
    cs.src[i] = srcs[i];
    cs.dst[i] = dsts[i];
    cs.n4[i] = (int)(ns[i] / 4);
    cs.cum[i] = cum;
    cum += (cs.n4[i] + 255) / 256;
  }
  cs.cum[8] = cum;
  cvt_all<<<dim3(cum), 256, 0, stream>>>(cs);

  const unsigned gm = TOKENS / 128;

  // fused down-projection: x -> qc | kvc | krope  (N=2112, padded grid 17)
  gemm_nt<5><<<dim3(17, gm), 256, 0, stream>>>(x_h, wA_h, qc_h, kvc_h, krope_h,
                                               TOKENS, 2112, DIM);
  // fused RMSNorm(qc) + RMSNorm(kvc) + rope_k
  rms_rope<<<dim3(2 * TOKENS + TOKENS * 32 / 256), 256, 0, stream>>>(
      qc_h, q_norm_w, kvc_h, kv_norm_w, krope_h);
  // fused up-projections: qc -> qnope|qpe ; kvc -> knope + vT
  gemm_up<<<dim3(24 + 32, gm), 256, 0, stream>>>(qc_h, wquqr_h, kvc_h, wkvu_h,
                                                 qnope_h, qpe_h, knope_h, vT_h);
  // attention (RoPE on Q applied in-kernel; 1024 blocks, longest-first)
  mla_attn<<<dim3(1024), 256, 0, stream>>>(qnope_h, qpe_h, knope_h, krope_h, vT_h, attn_h);
  // output projection (fp32 out)
  gemm_nt<1><<<dim3(16, gm), 256, 0, stream>>>(attn_h, wo_h, out, nullptr, nullptr,
                                               TOKENS, DIM, NH * DV);
}

// Round 7
// 472.432 us; speedup vs baseline: 1.1272x; 1.0071x over previous
//
#include <hip/hip_runtime.h>
#include <stdint.h>

typedef _Float16 f16x8 __attribute__((ext_vector_type(8)));
typedef _Float16 f16x4 __attribute__((ext_vector_type(4)));
typedef float fx4 __attribute__((ext_vector_type(4)));

static constexpr int S_LEN = 2048;
static constexpr int BATCH = 2;
static constexpr int TOKENS = BATCH * S_LEN;   // 4096
static constexpr int DIM = 2048;
static constexpr int NH = 16;
static constexpr int QR = 1536;
static constexpr int KVR = 512;
static constexpr int DN = 128;
static constexpr int DR = 64;
static constexpr int DV = 128;

// async global->LDS, 16B per lane; LDS dest = wave-uniform base, HW adds lane*16
__device__ __forceinline__ void async16(const _Float16* g, _Float16* lds_base_uniform) {
  __builtin_amdgcn_global_load_lds(
      (const __attribute__((address_space(1))) void*)g,
      (__attribute__((address_space(3))) void*)lds_base_uniform, 16, 0, 0);
}

// raw barrier WITHOUT the implicit vmcnt(0) drain of __syncthreads
__device__ __forceinline__ void bar() {
  asm volatile("" ::: "memory");
  __builtin_amdgcn_s_barrier();
  asm volatile("" ::: "memory");
}
#define VMWAIT(n) asm volatile("s_waitcnt vmcnt(" #n ")" ::: "memory")

// intra-16-lane rotate via DPP (VALU, ~4cyc vs ~35cyc ds_swizzle)
#define ROR16(x, ctrl) \
  __uint_as_float(__builtin_amdgcn_update_dpp(__float_as_uint(x), __float_as_uint(x), \
                                              (ctrl), 0xF, 0xF, false))

// sin/cos via v_sin/v_cos (input = revolutions), manual range reduction
__device__ __forceinline__ void sincos_rev(float ang, float* sn, float* cs) {
  float rev = ang * 0.15915494309189535f;
  rev -= floorf(rev);
  *sn = __builtin_amdgcn_sinf(rev);   // sin(2*pi*rev)
  *cs = __builtin_amdgcn_cosf(rev);
}

// ---------------- fused f32 -> f16 conversion (+ optional per-col norm fold)
struct CvtSegs {
  const float* src[8];
  _Float16* dst[8];
  const float* nw[8];   // per-column weight to fold (or nullptr)
  int nmod[8];          // column count (multiple of 4)
  int n4[8];
  int cum[9];
};
__global__ __launch_bounds__(256) void cvt_all(CvtSegs s) {
  const int b = blockIdx.x;
  int seg = 0;
#pragma unroll
  for (int k = 0; k < 7; ++k) seg += (b >= s.cum[seg + 1]) ? 1 : 0;
  const int i = (b - s.cum[seg]) * 256 + threadIdx.x;
  if (i >= s.n4[seg]) return;
  fx4 v = *(const fx4*)(s.src[seg] + (size_t)i * 4);
  if (s.nw[seg]) {
    const int c0 = (int)(((size_t)i * 4) % (size_t)s.nmod[seg]);
    fx4 wv = *(const fx4*)(s.nw[seg] + c0);
    v[0] *= wv[0]; v[1] *= wv[1]; v[2] *= wv[2]; v[3] *= wv[3];
  }
  f16x4 o;
  o[0] = (_Float16)v[0]; o[1] = (_Float16)v[1];
  o[2] = (_Float16)v[2]; o[3] = (_Float16)v[3];
  *(f16x4*)(s.dst[seg] + (size_t)i * 4) = o;
}

// ---------------- NT GEMM, 3-buffer LDS, counted vmcnt (no drain) ----------
// C[M,N] = A[M,K] * W[N,K]^T.  128x128 tile, BK=32.
// MODE 1: f32 C0 (out-proj).
// MODE 5: down-proj split: col<1536 -> qc[.,1536]; <2048 -> kvc[.,512];
//         <2112 -> krope[.,64] WITH RoPE applied in-epilogue.
template <int MODE>
__global__ __launch_bounds__(256) void gemm_nt(const _Float16* __restrict__ A,
                                               const _Float16* __restrict__ W,
                                               void* __restrict__ C0v,
                                               void* __restrict__ C1v,
                                               void* __restrict__ C2v,
                                               int M, int N, int K) {
  __shared__ __attribute__((aligned(16))) _Float16 As[3][128 * 32];
  __shared__ __attribute__((aligned(16))) _Float16 Ws[3][128 * 32];
  const int tid = threadIdx.x;
  const int lane = tid & 63;
  const int wave = tid >> 6;
  const int wr = (wave >> 1) * 64;
  const int wc = (wave & 1) * 64;
  const int m16 = lane & 15;
  const int quad = lane >> 4;
  const int m0 = blockIdx.y * 128;
  const int n0 = blockIdx.x * 128;

  auto stage = [&](int buf, int k0) {
#pragma unroll
    for (int p = 0; p < 2; ++p) {
      const int cb = p * 256 + wave * 64;   // wave-uniform chunk base
      const int ch = cb + lane;
      const int r = ch >> 2;
      const int c8 = (ch & 3) * 8;
      async16(A + (size_t)(m0 + r) * K + k0 + c8, &As[buf][cb * 8]);
      async16(W + (size_t)(n0 + r) * K + k0 + c8, &Ws[buf][cb * 8]);
    }
  };

  const fx4 fz = {0.f, 0.f, 0.f, 0.f};
  fx4 acc[4][4];
#pragma unroll
  for (int i = 0; i < 4; ++i)
#pragma unroll
    for (int j = 0; j < 4; ++j) acc[i][j] = fz;

  const int nkt = K >> 5;
  stage(0, 0);
  stage(1, 32);
  int cur = 0;
  for (int kt = 0; kt < nkt; ++kt) {
    if (kt + 1 < nkt) { VMWAIT(4); } else { VMWAIT(0); }
    bar();
    if (kt + 2 < nkt) {
      int b2 = cur + 2; if (b2 >= 3) b2 -= 3;
      stage(b2, (kt + 2) * 32);
    }
    const _Float16* as = As[cur];
    const _Float16* ws = Ws[cur];
    f16x8 af[4], wf[4];
#pragma unroll
    for (int i = 0; i < 4; ++i)
      af[i] = *(const f16x8*)(&as[(wr + i * 16 + m16) * 32 + quad * 8]);
#pragma unroll
    for (int j = 0; j < 4; ++j)
      wf[j] = *(const f16x8*)(&ws[(wc + j * 16 + m16) * 32 + quad * 8]);
#pragma unroll
    for (int i = 0; i < 4; ++i)
#pragma unroll
      for (int j = 0; j < 4; ++j)
        acc[i][j] = __builtin_amdgcn_mfma_f32_16x16x32_f16(af[i], wf[j], acc[i][j], 0, 0, 0);
    if (++cur == 3) cur = 0;
  }

#pragma unroll
  for (int j = 0; j < 4; ++j) {
    const int col = n0 + wc + j * 16 + m16;
    if (MODE == 5) {
      if (col < 2048) {
#pragma unroll
        for (int i = 0; i < 4; ++i)
#pragma unroll
          for (int r = 0; r < 4; ++r) {
            const size_t row = (size_t)(m0 + wr + i * 16 + quad * 4 + r);
            const _Float16 v = (_Float16)acc[i][j][r];
            if (col < 1536) ((_Float16*)C0v)[row * 1536 + col] = v;
            else            ((_Float16*)C1v)[row * 512 + col - 1536] = v;
          }
      } else if (col < 2112) {
        // k_rope with RoPE fused (pair = adjacent lanes, exchange via shfl_xor 1)
        const int d = col - 2048;
        const int pidx = d >> 1;
        const bool odd = (d & 1);
        const float fr = exp2f(-(float)pidx * 0.4152410118609203f);
#pragma unroll
        for (int i = 0; i < 4; ++i)
#pragma unroll
          for (int r = 0; r < 4; ++r) {
            const size_t row = (size_t)(m0 + wr + i * 16 + quad * 4 + r);
            const int spos = (int)(row & (S_LEN - 1));
            float sn, cs;
            sincos_rev((float)spos * fr, &sn, &cs);
            const float own = acc[i][j][r];
            const float oth = __shfl_xor(own, 1);
            const float res = odd ? (oth * sn + own * cs) : (own * cs - oth * sn);
            ((_Float16*)C2v)[row * 64 + d] = (_Float16)res;
          }
      }
    } else {
      if (col < N) {
#pragma unroll
        for (int i = 0; i < 4; ++i)
#pragma unroll
          for (int r = 0; r < 4; ++r) {
            const size_t row = (size_t)(m0 + wr + i * 16 + quad * 4 + r);
            ((float*)C0v)[row * N + col] = acc[i][j][r];
          }
      }
    }
  }
}

// ---------------- fused up-projections with in-GEMM RMSNorm ----------------
// Norm weight is pre-folded into W columns (at cvt). The rsqrt row factor is
// computed from the staged A fragments (sum x^2 alongside MFMA; quad-reduce)
// and applied to the output rows in the epilogue (row scale commutes).
// blockIdx.x < 24: qc[4096,1536] x wquqr^T -> qnope|qpe
// else           : kvc[4096,512] x wkvu^T  -> knope + vT (transposed)
__global__ __launch_bounds__(256) void gemm_up(
    const _Float16* __restrict__ qc, const _Float16* __restrict__ wqu,
    const _Float16* __restrict__ kvc, const _Float16* __restrict__ wkvu,
    _Float16* __restrict__ qnope, _Float16* __restrict__ qpe,
    _Float16* __restrict__ knope, _Float16* __restrict__ vT) {
  __shared__ __attribute__((aligned(16))) _Float16 As[3][128 * 32];
  __shared__ __attribute__((aligned(16))) _Float16 Ws[3][128 * 32];
  const int tid = threadIdx.x;
  const int lane = tid & 63;
  const int wave = tid >> 6;
  const int wr = (wave >> 1) * 64;
  const int wc = (wave & 1) * 64;
  const int m16 = lane & 15;
  const int quad = lane >> 4;
  const int m0 = blockIdx.y * 128;
  const bool isq = (blockIdx.x < 24);
  const int n0 = (isq ? blockIdx.x : blockIdx.x - 24) * 128;
  const _Float16* A = isq ? qc : kvc;
  const _Float16* W = isq ? wqu : wkvu;
  const int K = isq ? QR : KVR;

  auto stage = [&](int buf, int k0) {
#pragma unroll
    for (int p = 0; p < 2; ++p) {
      const int cb = p * 256 + wave * 64;
      const int ch = cb + lane;
      const int r = ch >> 2;
      const int c8 = (ch & 3) * 8;
      async16(A + (size_t)(m0 + r) * K + k0 + c8, &As[buf][cb * 8]);
      async16(W + (size_t)(n0 + r) * K + k0 + c8, &Ws[buf][cb * 8]);
    }
  };

  const fx4 fz = {0.f, 0.f, 0.f, 0.f};
  fx4 acc[4][4];
#pragma unroll
  for (int i = 0; i < 4; ++i)
#pragma unroll
    for (int j = 0; j < 4; ++j) acc[i][j] = fz;
  float ssq[4] = {0.f, 0.f, 0.f, 0.f};

  const int nkt = K >> 5;                  // 48 or 16
  stage(0, 0);
  stage(1, 32);
  int cur = 0;
  for (int kt = 0; kt < nkt; ++kt) {
    if (kt + 1 < nkt) { VMWAIT(4); } else { VMWAIT(0); }
    bar();
    if (kt + 2 < nkt) {
      int b2 = cur + 2; if (b2 >= 3) b2 -= 3;
      stage(b2, (kt + 2) * 32);
    }
    const _Float16* as = As[cur];
    const _Float16* ws = Ws[cur];
    f16x8 af[4], wf[4];
#pragma unroll
    for (int i = 0; i < 4; ++i)
      af[i] = *(const f16x8*)(&as[(wr + i * 16 + m16) * 32 + quad * 8]);
#pragma unroll
    for (int j = 0; j < 4; ++j)
      wf[j] = *(const f16x8*)(&ws[(wc + j * 16 + m16) * 32 + quad * 8]);
#pragma unroll
    for (int i = 0; i < 4; ++i)
#pragma unroll
      for (int j = 0; j < 4; ++j)
        acc[i][j] = __builtin_amdgcn_mfma_f32_16x16x32_f16(af[i], wf[j], acc[i][j], 0, 0, 0);
    // sum-of-squares of the A slice this lane holds (cols quad*8..+7 of chunk)
#pragma unroll
    for (int i = 0; i < 4; ++i) {
      float s0 = 0.f;
#pragma unroll
      for (int e = 0; e < 8; ++e) { const float xv = (float)af[i][e]; s0 += xv * xv; }
      ssq[i] += s0;
    }
    if (++cur == 3) cur = 0;
  }

  // per-row rsqrt factors; A-layout rows are m16-indexed, acc rows quad*4+r
  const float invK = 1.0f / (float)K;
  float rsq[4][4];
#pragma unroll
  for (int i = 0; i < 4; ++i) {
    float ss = ssq[i];
    ss += __shfl_xor(ss, 16);
    ss += __shfl_xor(ss, 32);               // all quads: full row sum
    const float rv = rsqrtf(ss * invK + 1e-6f);
#pragma unroll
    for (int r = 0; r < 4; ++r) rsq[i][r] = __shfl(rv, quad * 4 + r);
  }

#pragma unroll
  for (int j = 0; j < 4; ++j) {
    const int col = n0 + wc + j * 16 + m16;
    if (isq) {
#pragma unroll
      for (int i = 0; i < 4; ++i)
#pragma unroll
        for (int r = 0; r < 4; ++r) {
          const size_t row = (size_t)(m0 + wr + i * 16 + quad * 4 + r);
          const _Float16 v = (_Float16)(acc[i][j][r] * rsq[i][r]);
          if (col < 2048) qnope[row * 2048 + col] = v;
          else qpe[row * 1024 + col - 2048] = v;
        }
    } else {
      const int head = col >> 8;
      const int sub = col & 255;
      if (sub < 128) {
#pragma unroll
        for (int i = 0; i < 4; ++i)
#pragma unroll
          for (int r = 0; r < 4; ++r)
            knope[(size_t)(m0 + wr + i * 16 + quad * 4 + r) * 2048 + head * 128 + sub] =
                (_Float16)(acc[i][j][r] * rsq[i][r]);
      } else {
        const int dv = sub - 128;
#pragma unroll
        for (int i = 0; i < 4; ++i) {
          f16x4 v;
#pragma unroll
          for (int r = 0; r < 4; ++r) v[r] = (_Float16)(acc[i][j][r] * rsq[i][r]);
          *(f16x4*)(&vT[(size_t)(head * 128 + dv) * TOKENS + m0 + wr + i * 16 + quad * 4]) = v;
        }
      }
    }
  }
}

// ---------------- causal flash attention v9 --------------------------------
// 8-wave blocks (512 thr), 128 q-rows (wave owns 16), grid = B*NH*16 = 512,
// longest-first (q16 = 15 - bid>>5). Same KV staging volume per tile now
// amortized over 2x rows; 2 blocks/CU -> 16 waves/CU (~50% occupancy).
// LDS 50KB: 2-buf K(24K) + V(16K) + P(10K). Vs XOR-swizzled. In-reg Q-RoPE,
// DPP softmax (max chain only on growth), l-sum via ones-column MFMA.
__global__ __launch_bounds__(512, 2) void mla_attn(
    const _Float16* __restrict__ qn,   // [T, NH*128]
    const _Float16* __restrict__ qp,   // [T, NH*64]  RAW (rope applied here)
    const _Float16* __restrict__ kn,   // [T, NH*128]
    const _Float16* __restrict__ kr,   // [T, 64]     roped
    const _Float16* __restrict__ vT,   // [NH*128, T]
    _Float16* __restrict__ out)        // [T, NH*128]
{
  __shared__ __attribute__((aligned(16))) _Float16 Ks[2][768 * 8];  // 24 KB
  __shared__ __attribute__((aligned(16))) _Float16 Vs[2][512 * 8];  // 16 KB
  __shared__ __attribute__((aligned(16))) _Float16 Ps[8][16][40];   // 10 KB

  const int bid = blockIdx.x;          // 512 = 16 q-tiles (longest first) x 32 (b,h)
  const int j = bid >> 5;
  const int bh = bid & 31;
  const int b = bh >> 4;
  const int h = bh & 15;
  const int q16 = 15 - j;              // longest-first
  const int qb = q16 * 128;
  const int tok0 = b * S_LEN;

  const int tid = threadIdx.x;
  const int lane = tid & 63;
  const int wave = tid >> 6;           // 0..7
  const int m16 = lane & 15;
  const int quad = lane >> 4;
  const int R0 = qb + wave * 16;

  auto stageKV = [&](int buf, int kbase) {
#pragma unroll
    for (int jj = 0; jj < 3; ++jj) {
      const int idx = wave * 3 + jj;          // 0..23; 20 used
      if (idx < 12) {
        const int ch = idx * 2 + (lane >> 5);
        const int key = lane & 31;
        const _Float16* g = (ch < 16)
            ? kn + (size_t)(tok0 + kbase + key) * 2048 + h * 128 + ch * 8
            : kr + (size_t)(tok0 + kbase + key) * 64 + (ch - 16) * 8;
        async16(g, &Ks[buf][idx * 512]);
      } else if (idx < 20) {
        const int iv = idx - 12;              // 0..7
        const int p = iv * 64 + lane;
        const int L = p ^ ((p >> 3) & 3);     // involutive source pre-swizzle
        const int dv = L >> 2;
        const int qcc = L & 3;
        async16(vT + (size_t)(h * 128 + dv) * TOKENS + tok0 + kbase + qcc * 8,
                &Vs[buf][iv * 512]);
      }
    }
  };

  const float scale2 = 0.07216878364870323f * 1.4426950408889634f;  // /sqrt(192), log2 dom
  const fx4 fz = {0.f, 0.f, 0.f, 0.f};

  // ---- Q fragments (A-layout); RoPE applied to the qp fragments in-reg ----
  f16x8 qf[6];
  {
    const int srow = qb + wave * 16 + m16;     // seq position (0..2047)
    const size_t t = (size_t)(tok0 + srow);
#pragma unroll
    for (int kk = 0; kk < 4; ++kk)
      qf[kk] = *(const f16x8*)(qn + t * 2048 + h * 128 + kk * 32 + quad * 8);
#pragma unroll
    for (int kk = 0; kk < 2; ++kk) {
      f16x8 v = *(const f16x8*)(qp + t * 1024 + h * 64 + kk * 32 + quad * 8);
      f16x8 o;
      const int i0 = kk * 16 + quad * 4;       // rope pair index base
#pragma unroll
      for (int jj = 0; jj < 4; ++jj) {
        const float ang = (float)srow * exp2f(-(float)(i0 + jj) * 0.4152410118609203f);
        float sn, cs;
        sincos_rev(ang, &sn, &cs);
        const float x1 = (float)v[2 * jj], x2 = (float)v[2 * jj + 1];
        o[2 * jj]     = (_Float16)(x1 * cs - x2 * sn);
        o[2 * jj + 1] = (_Float16)(x1 * sn + x2 * cs);
      }
      qf[4 + kk] = o;
    }
  }

  fx4 oacc[9];                         // [8] accumulates row-sums (P x ones)
#pragma unroll
  for (int n = 0; n < 9; ++n) oacc[n] = fz;
  float mst[4];
#pragma unroll
  for (int r = 0; r < 4; ++r) mst[r] = -3.0e38f;
  f16x8 vones;
#pragma unroll
  for (int e = 0; e < 8; ++e) vones[e] = (_Float16)1.0f;

  const int nkt = (qb >> 5) + 4;       // key tiles: 0 .. qb+127 (4..64)

  stageKV(0, 0);
  for (int kt = 0; kt < nkt; ++kt) {
    const int kbase = kt * 32;
    __syncthreads();
    if (kt + 1 < nkt) stageKV((kt + 1) & 1, kbase + 32);

    const bool live = (kbase <= R0 + 15);
    if (!live) continue;
    const _Float16* ks = Ks[kt & 1];
    const _Float16* vs = Vs[kt & 1];

    // ---- S = Q K^T ----
    fx4 sc[2];
    sc[0] = fz; sc[1] = fz;
    __builtin_amdgcn_s_setprio(1);
#pragma unroll
    for (int kk = 0; kk < 6; ++kk) {
#pragma unroll
      for (int n = 0; n < 2; ++n) {
        f16x8 kf = *(const f16x8*)(&ks[(kk * 128 + quad * 32 + n * 16 + m16) * 8]);
        sc[n] = __builtin_amdgcn_mfma_f32_16x16x32_f16(qf[kk], kf, sc[n], 0, 0, 0);
      }
    }
    __builtin_amdgcn_s_setprio(0);

    // V fragments from LDS (swizzled read)
    f16x8 vf[8];
#pragma unroll
    for (int n8 = 0; n8 < 8; ++n8) {
      const int c0 = (n8 * 16 + m16) * 4 + quad;
      vf[n8] = *(const f16x8*)(&vs[(c0 ^ ((c0 >> 3) & 3)) * 8]);
    }

    // ---- online softmax: max-reduce only on growth; no sum-reduce at all ----
    const bool needmask = (kbase + 31 > R0);
    float alpha[4];
    bool any_upd = false;
#pragma unroll
    for (int r = 0; r < 4; ++r) {
      float v0 = sc[0][r] * scale2;
      float v1 = sc[1][r] * scale2;
      if (needmask) {
        const int qrow = R0 + quad * 4 + r;
        if (kbase + m16 > qrow)      v0 = -3.0e38f;
        if (kbase + 16 + m16 > qrow) v1 = -3.0e38f;
      }
      const float pre = fmaxf(v0, v1);
      float al = 1.0f;
      if (__any(pre > mst[r] + 10.0f)) {       // rare after warm-up
        float mx = pre;
        mx = fmaxf(mx, ROR16(mx, 0x128));
        mx = fmaxf(mx, ROR16(mx, 0x124));
        mx = fmaxf(mx, ROR16(mx, 0x122));
        mx = fmaxf(mx, ROR16(mx, 0x121));
        const float mn = fmaxf(mst[r], mx);
        al = exp2f(mst[r] - mn);
        mst[r] = mn;
        any_upd = true;
      }
      alpha[r] = al;
      const float p0 = exp2f(v0 - mst[r]);
      const float p1 = exp2f(v1 - mst[r]);
      _Float16* pr = &Ps[wave][quad * 4 + r][0];
      pr[m16] = (_Float16)p0;
      pr[16 + m16] = (_Float16)p1;
    }
    if (any_upd) {
#pragma unroll
      for (int n8 = 0; n8 < 9; ++n8)
#pragma unroll
        for (int r = 0; r < 4; ++r) oacc[n8][r] *= alpha[r];
    }

    // ---- O += P V ; row-sums accumulate via ones-column MFMA ----
    f16x8 pf = *(const f16x8*)(&Ps[wave][m16][quad * 8]);
    __builtin_amdgcn_s_setprio(1);
#pragma unroll
    for (int n8 = 0; n8 < 8; ++n8)
      oacc[n8] = __builtin_amdgcn_mfma_f32_16x16x32_f16(pf, vf[n8], oacc[n8], 0, 0, 0);
    oacc[8] = __builtin_amdgcn_mfma_f32_16x16x32_f16(pf, vones, oacc[8], 0, 0, 0);
    __builtin_amdgcn_s_setprio(0);
  }

  // ---- epilogue: normalize by oacc[8] (row sums; all cols equal) ----
  float inv[4];
#pragma unroll
  for (int r = 0; r < 4; ++r) inv[r] = 1.0f / oacc[8][r];
#pragma unroll
  for (int n8 = 0; n8 < 8; ++n8) {
#pragma unroll
    for (int r = 0; r < 4; ++r) {
      const size_t t = (size_t)(tok0 + qb + wave * 16 + quad * 4 + r);
      out[t * 2048 + h * 128 + n8 * 16 + m16] = (_Float16)(oacc[n8][r] * inv[r]);
    }
  }
}

// ---------------- launch ----------------------------------------------------
extern "C" void kernel_launch(void* const* d_in, const int* in_sizes, int n_in,
                              void* d_out, int out_size, void* d_ws, size_t ws_size,
                              hipStream_t stream) {
  const float* x         = (const float*)d_in[0];
  const float* wq_down   = (const float*)d_in[1];
  const float* q_norm_w  = (const float*)d_in[2];
  const float* wq_up     = (const float*)d_in[3];
  const float* wq_rope   = (const float*)d_in[4];
  const float* wkv_down  = (const float*)d_in[5];
  const float* kv_norm_w = (const float*)d_in[6];
  const float* wkv_up    = (const float*)d_in[7];
  const float* wk_rope   = (const float*)d_in[8];
  const float* wo        = (const float*)d_in[9];
  float* out = (float*)d_out;

  char* ws = (char*)d_ws;
  size_t off = 0;
  auto alloc = [&](size_t bytes) {
    char* p = ws + off;
    off += (bytes + 255) & ~(size_t)255;
    return p;
  };
  _Float16* x_h     = (_Float16*)alloc((size_t)TOKENS * DIM * 2);
  _Float16* wA_h    = (_Float16*)alloc((size_t)2176 * DIM * 2);      // wq_down|wkv_down|wk_rope (+pad)
  _Float16* wquqr_h = (_Float16*)alloc((size_t)3072 * QR * 2);       // (wq_up|wq_rope) . q_norm
  _Float16* wkvu_h  = (_Float16*)alloc((size_t)NH * 256 * KVR * 2);  // wkv_up . kv_norm
  _Float16* wo_h    = (_Float16*)alloc((size_t)DIM * NH * DV * 2);
  _Float16* qc_h    = (_Float16*)alloc((size_t)TOKENS * QR * 2);     // RAW (un-normalized)
  _Float16* kvc_h   = (_Float16*)alloc((size_t)TOKENS * KVR * 2);    // RAW
  _Float16* qnope_h = (_Float16*)alloc((size_t)TOKENS * 2048 * 2);
  _Float16* qpe_h   = (_Float16*)alloc((size_t)TOKENS * 1024 * 2);
  _Float16* knope_h = (_Float16*)alloc((size_t)TOKENS * 2048 * 2);
  _Float16* vT_h    = (_Float16*)alloc((size_t)2048 * TOKENS * 2);
  _Float16* krope_h = (_Float16*)alloc((size_t)TOKENS * DR * 2);     // roped in down-proj
  _Float16* attn_h  = (_Float16*)alloc((size_t)TOKENS * 2048 * 2);

  // ---- one fused conversion dispatch (norm weights folded into up-proj W) --
  CvtSegs cs;
  const float* srcs[8] = {x, wq_down, wq_up, wq_rope, wkv_down, wk_rope, wkv_up, wo};
  _Float16* dsts[8] = {x_h, wA_h, wquqr_h, wquqr_h + (size_t)2048 * QR,
                       wA_h + (size_t)1536 * DIM, wA_h + (size_t)2048 * DIM,
                       wkvu_h, wo_h};
  const float* nws[8] = {nullptr, nullptr, q_norm_w, q_norm_w, nullptr, nullptr,
                         kv_norm_w, nullptr};
  const int nmods[8] = {4, 4, QR, QR, 4, 4, KVR, 4};
  const size_t ns[8] = {(size_t)TOKENS * DIM, (size_t)QR * DIM, (size_t)2048 * QR,
                        (size_t)1024 * QR, (size_t)KVR * DIM, (size_t)DR * DIM,
                        (size_t)NH * 256 * KVR, (size_t)DIM * NH * DV};
  int cum = 0;
  for (int i = 0; i < 8; ++i) {
    cs.src[i] = srcs[i];
    cs.dst[i] = dsts[i];
    cs.nw[i] = nws[i];
    cs.nmod[i] = nmods[i];
    cs.n4[i] = (int)(ns[i] / 4);
    cs.cum[i] = cum;
    cum += (cs.n4[i] + 255) / 256;
  }
  cs.cum[8] = cum;
  cvt_all<<<dim3(cum), 256, 0, stream>>>(cs);

  const unsigned gm = TOKENS / 128;

  // fused down-projection: x -> qc | kvc | krope(+RoPE)  (N=2112, grid 17)
  gemm_nt<5><<<dim3(17, gm), 256, 0, stream>>>(x_h, wA_h, qc_h, kvc_h, krope_h,
                                               TOKENS, 2112, DIM);
  // fused up-projections with in-GEMM RMSNorm: qc -> qnope|qpe ; kvc -> knope+vT
  gemm_up<<<dim3(24 + 32, gm), 256, 0, stream>>>(qc_h, wquqr_h, kvc_h, wkvu_h,
                                                 qnope_h, qpe_h, knope_h, vT_h);
  // attention: 512 blocks x 8 waves (128 q-rows each), longest-first
  mla_attn<<<dim3(512), 512, 0, stream>>>(qnope_h, qpe_h, knope_h, krope_h, vT_h, attn_h);
  // output projection (fp32 out)
  gemm_nt<1><<<dim3(16, gm), 256, 0, stream>>>(attn_h, wo_h, out, nullptr, nullptr,
                                               TOKENS, DIM, NH * DV);
}